// Round 5
// baseline (161108.276 us; speedup 1.0000x reference)
//
#include <hip/hip_runtime.h>

// OR_LSTM Round 13: XCD-local exchange, FAIL-SAFE edition.
// B=32,T=128,D=16,H=256,WS=8,OUT=8. 127 iterations, 8-slot window pipeline,
// 256 wgs = 8 slots x 32 col-groups, TPB=256, 1 wg/CU (LDS-forced).
// R12 (slot==XCD, sc0-only exchange) hung with no profile. R13 guards every
// unproven element:
//  (a) XCC id via __builtin_amdgcn_s_getreg(63508) (id=20,off=0,size=32) --
//      compile-safe builtin, no asm hwreg-name parsing.
//  (b) role-claim VERIFICATION: grid barrier, then check all 8 per-XCD
//      counters == 32. Any skew -> fall back to R11 blockIdx mapping
//      (proven-correct). Decision deterministic and global.
//  (c) scope-adaptive exchange: claimed -> sc0-only (XCD-local L2);
//      fallback -> proven sc0 sc1 (MALL). Tag polls ESCALATE to sc0 sc1
//      after 1024 spins, so stale-L1 serving can't spin forever.
// colX (cross-slot out-column feedback) stays MALL sc0 sc1 always.

#define NWG 256
#define TPB 256

typedef float f32x4 __attribute__((ext_vector_type(4)));
typedef _Float16 f16x8 __attribute__((ext_vector_type(8)));
typedef unsigned u32x2 __attribute__((ext_vector_type(2)));

// ---- workspace byte layout ----
#define CTRL_BYTES 4096
#define OFF_W0H   36864      // f16 [1024 cols][296]   (init-only source)
#define OFF_W1AH  643072     // f16 [1024][256]        (init-only source)
#define OFF_W1AL  1167360
#define OFF_W1BH  1691648
#define OFF_W1BL  2215936
// overlays (live after init grid barriers; zeroed in-kernel between them):
#define OFF_H0X   OFF_W1AH   // u32 [2 par][8 sl][32 r][256 u] {hi16,lo16+tag}
#define OFF_H1X   OFF_W1AL   // u32 [2 par][8 sl][32 r][256 u] {hi16,lo16+tag}
// never-written-by-prep region (zeroed by memsetAsync):
#define OFF_COLX  2740224    // u32 [120 t][32 r][8 o]  {hi16, lo16|bit0}
#define COLX_BYTES 122880

// ---- ctrl u32 indices ----
#define IB0_U 16             // claim-verification barrier
#define IB1_U 32             // weights-read-done barrier
#define IB2_U 48             // zeroing-done barrier
#define XC_U(x) ((4 + (x)) * 16)   // 8 XCD rank counters (idx 64..176)

// ---- dynamic LDS byte layout (<= 160KB) ----
#define L_W0H   0        // f16 [32][296]
#define L_W1AH  18944    // f16 [32][264]
#define L_W1AL  35840
#define L_W1BH  52736
#define L_W1BL  69632
#define L_ABH   86528    // f16 [32 rows][296]: x(0..15)|zero(16..31)|h0(32..287)
#define L_ABL   105472
#define L_H1H   124416   // f16 [32][264]
#define L_GATES 141312   // f32 [32][33]
#define L_WLIN  145536   // f32 [8][260]
#define L_BASE  155008   // f32 [32][8]  (u32[0..2] = {xcd,rank,ok} at init)
#define L_B0    156032
#define L_B1    156160
#define L_BLIN  156288
#define SMEM_BYTES 156320

#define SPIN_ESC 1024    // polls before escalating to MALL-scope loads

__device__ __forceinline__ float sigf(float x) { return 1.0f / (1.0f + __expf(-x)); }
__device__ __forceinline__ float tanhfast(float x) {
  float e = __expf(2.0f * x);
  return 1.0f - 2.0f / (e + 1.0f);
}
__device__ __forceinline__ unsigned f16u(_Float16 h) {
  union { _Float16 h; unsigned short u; } c; c.h = h; return c.u;
}
__device__ __forceinline__ float uf16(unsigned u) {
  union { unsigned short s; _Float16 h; } c; c.s = (unsigned short)u; return (float)c.h;
}
__device__ __forceinline__ unsigned fbits(float x) {
  union { float f; unsigned u; } c; c.f = x; return c.u;
}
__device__ __forceinline__ void splitpack(float x0, float x1, unsigned& hw, unsigned& lw) {
  const _Float16 a = (_Float16)x0, b = (_Float16)x1;
  hw = f16u(a) | (f16u(b) << 16);
  lw = f16u((_Float16)(x0 - (float)a)) | (f16u((_Float16)(x1 - (float)b)) << 16);
}

__device__ __forceinline__ unsigned rload(const unsigned* p) {
  return __hip_atomic_load(p, __ATOMIC_RELAXED, __HIP_MEMORY_SCOPE_AGENT);
}
// MALL (device-coherent) ops: sc0 sc1 -- the R6/R11-proven primitives.
__device__ __forceinline__ void mall_store_u32(unsigned* p, unsigned v) {
  asm volatile("global_store_dword %0, %1, off sc0 sc1" :: "v"(p), "v"(v) : "memory");
}
__device__ __forceinline__ void mall_load2(const void* p, unsigned& x, unsigned& y) {
  u32x2 v;
  asm volatile("global_load_dwordx2 %0, %1, off sc0 sc1\n\ts_waitcnt vmcnt(0)"
               : "=v"(v) : "v"(p) : "memory");
  x = v.x; y = v.y;
}
__device__ __forceinline__ void mall_load8x4(const void* p, f32x4& a0, f32x4& a1,
                                             f32x4& a2, f32x4& a3, f32x4& a4,
                                             f32x4& a5, f32x4& a6, f32x4& a7) {
  asm volatile(
      "global_load_dwordx4 %0, %8, off sc0 sc1\n\t"
      "global_load_dwordx4 %1, %8, off offset:16 sc0 sc1\n\t"
      "global_load_dwordx4 %2, %8, off offset:32 sc0 sc1\n\t"
      "global_load_dwordx4 %3, %8, off offset:48 sc0 sc1\n\t"
      "global_load_dwordx4 %4, %8, off offset:64 sc0 sc1\n\t"
      "global_load_dwordx4 %5, %8, off offset:80 sc0 sc1\n\t"
      "global_load_dwordx4 %6, %8, off offset:96 sc0 sc1\n\t"
      "global_load_dwordx4 %7, %8, off offset:112 sc0 sc1\n\t"
      "s_waitcnt vmcnt(0)"
      : "=&v"(a0), "=&v"(a1), "=&v"(a2), "=&v"(a3),
        "=&v"(a4), "=&v"(a5), "=&v"(a6), "=&v"(a7)
      : "v"(p) : "memory");
}
// XCD-local (intra-L2) ops: sc0 only (L1 bypass; producer+consumer share L2)
__device__ __forceinline__ void l2_store_u32(unsigned* p, unsigned v) {
  asm volatile("global_store_dword %0, %1, off sc0" :: "v"(p), "v"(v) : "memory");
}
__device__ __forceinline__ void l2_load8x4(const void* p, f32x4& a0, f32x4& a1,
                                           f32x4& a2, f32x4& a3, f32x4& a4,
                                           f32x4& a5, f32x4& a6, f32x4& a7) {
  asm volatile(
      "global_load_dwordx4 %0, %8, off sc0\n\t"
      "global_load_dwordx4 %1, %8, off offset:16 sc0\n\t"
      "global_load_dwordx4 %2, %8, off offset:32 sc0\n\t"
      "global_load_dwordx4 %3, %8, off offset:48 sc0\n\t"
      "global_load_dwordx4 %4, %8, off offset:64 sc0\n\t"
      "global_load_dwordx4 %5, %8, off offset:80 sc0\n\t"
      "global_load_dwordx4 %6, %8, off offset:96 sc0\n\t"
      "global_load_dwordx4 %7, %8, off offset:112 sc0\n\t"
      "s_waitcnt vmcnt(0)"
      : "=&v"(a0), "=&v"(a1), "=&v"(a2), "=&v"(a3),
        "=&v"(a4), "=&v"(a5), "=&v"(a6), "=&v"(a7)
      : "v"(p) : "memory");
}
__device__ __forceinline__ void x_store_u32(unsigned* p, unsigned v, bool fast) {
  if (fast) l2_store_u32(p, v); else mall_store_u32(p, v);
}
__device__ __forceinline__ void vmdrain() {
  asm volatile("s_waitcnt vmcnt(0)" ::: "memory");
}
__device__ __forceinline__ f32x4 mfma16(f16x8 a, f16x8 b, f32x4 c) {
  return __builtin_amdgcn_mfma_f32_16x16x32_f16(a, b, c, 0, 0, 0);
}

// tag checks: h0X/h1X words carry tag in bits 17:16
#define TG4(vv) (((fbits(vv.x) >> 16) & 3u) == tagv) & (((fbits(vv.y) >> 16) & 3u) == tagv) & \
                (((fbits(vv.z) >> 16) & 3u) == tagv) & (((fbits(vv.w) >> 16) & 3u) == tagv)
#define UNPK(vv, i2) {                                              \
    const unsigned w0 = fbits(vv.x), w1 = fbits(vv.y);              \
    const unsigned w2 = fbits(vv.z), w3 = fbits(vv.w);              \
    ah32[(i2)]     = (w0 & 0xffffu) | (w1 << 16);                   \
    ah32[(i2) + 1] = (w2 & 0xffffu) | (w3 << 16);                   \
    al32[(i2)]     = (w0 >> 16) | (w1 & 0xffff0000u);               \
    al32[(i2) + 1] = (w2 >> 16) | (w3 & 0xffff0000u); }
#define PKH(vv, i2) {                                               \
    dst[(i2)]     = (fbits(vv.x) & 0xffffu) | ((fbits(vv.y) & 0xffffu) << 16); \
    dst[(i2) + 1] = (fbits(vv.z) & 0xffffu) | ((fbits(vv.w) & 0xffffu) << 16); }
// escalating tag-poll gather: sc0 first (if fastx), MALL after SPIN_ESC
#define POLL8(srcp)                                                  \
  { int spins = 0;                                                   \
    while (true) {                                                   \
      if (fastx && spins < SPIN_ESC)                                 \
        l2_load8x4(srcp, v0, v1, v2, v3, v4, v5, v6, v7);            \
      else                                                           \
        mall_load8x4(srcp, v0, v1, v2, v3, v4, v5, v6, v7);          \
      const unsigned ok = TG4(v0) & TG4(v1) & TG4(v2) & TG4(v3) &    \
                          TG4(v4) & TG4(v5) & TG4(v6) & TG4(v7);     \
      if (ok) break;                                                 \
      ++spins;                                                       \
    } }

// ---- prep (unchanged): pack weights into frag-ready f16 planes ----
__global__ __launch_bounds__(256) void lstm_prep(
    const float* __restrict__ Wih0, const float* __restrict__ Whh0,
    const float* __restrict__ Wih1, const float* __restrict__ Whh1,
    char* __restrict__ wsb) {
  const int i = blockIdx.x * 256 + threadIdx.x;
  _Float16* W0H = (_Float16*)(wsb + OFF_W0H);
  _Float16* W1AH = (_Float16*)(wsb + OFF_W1AH);
  _Float16* W1AL = (_Float16*)(wsb + OFF_W1AL);
  _Float16* W1BH = (_Float16*)(wsb + OFF_W1BH);
  _Float16* W1BL = (_Float16*)(wsb + OFF_W1BL);
  if (i < 1024 * 296) {           // W0 hi-only
    const int cg = i / 296, k = i - cg * 296;
    const int cw = cg >> 5, c = cg & 31;
    const int J = (c >> 3) * 256 + cw * 8 + (c & 7);
    float w = 0.f;
    if (k < 16) w = Wih0[J * 16 + k];
    else if (k >= 32 && k < 288) w = Whh0[J * 256 + (k - 32)];
    W0H[i] = (_Float16)w;
  }
  if (i < 1024 * 256) {           // W1A/W1B hi+lo
    const int cg = i >> 8, k = i & 255;
    const int cw = cg >> 5, c = cg & 31;
    const int J = (c >> 3) * 256 + cw * 8 + (c & 7);
    const float wa = Wih1[J * 256 + k];
    _Float16 h = (_Float16)wa;
    W1AH[i] = h; W1AL[i] = (_Float16)(wa - (float)h);
    const float wb = Whh1[J * 256 + k];
    h = (_Float16)wb;
    W1BH[i] = h; W1BL[i] = (_Float16)(wb - (float)h);
  }
}

__global__ __launch_bounds__(TPB, 1) void lstm_main(
    const float* __restrict__ traj,
    const float* __restrict__ bih0, const float* __restrict__ bhh0,
    const float* __restrict__ bih1, const float* __restrict__ bhh1,
    const float* __restrict__ Wlin, const float* __restrict__ blin,
    float* __restrict__ out, char* __restrict__ wsb) {
  extern __shared__ char smem[];
  _Float16* const W0H_  = (_Float16*)(smem + L_W0H);
  _Float16* const W1AH_ = (_Float16*)(smem + L_W1AH);
  _Float16* const W1AL_ = (_Float16*)(smem + L_W1AL);
  _Float16* const W1BH_ = (_Float16*)(smem + L_W1BH);
  _Float16* const W1BL_ = (_Float16*)(smem + L_W1BL);
  _Float16* const ABH_  = (_Float16*)(smem + L_ABH);
  _Float16* const ABL_  = (_Float16*)(smem + L_ABL);
  _Float16* const H1H_  = (_Float16*)(smem + L_H1H);
  float* const GATES_ = (float*)(smem + L_GATES);
  float* const WLIN_  = (float*)(smem + L_WLIN);
  float* const BASE_  = (float*)(smem + L_BASE);
  float* const B0_    = (float*)(smem + L_B0);
  float* const B1_    = (float*)(smem + L_B1);
  float* const BLIN_  = (float*)(smem + L_BLIN);

  const int tid = threadIdx.x;
  unsigned* ctrl = (unsigned*)wsb;
  unsigned* const h0x = (unsigned*)(wsb + OFF_H0X);
  unsigned* const h1x = (unsigned*)(wsb + OFF_H1X);
  unsigned* const colx = (unsigned*)(wsb + OFF_COLX);

  // ---- XCD role claim + VERIFICATION (fail-safe) ----
  // __builtin_amdgcn_s_getreg(63508): hwreg id=20 (XCC_ID), offset 0, size 32.
  if (tid == 0) {
    const unsigned x = (unsigned)__builtin_amdgcn_s_getreg(63508) & 7u;
    const unsigned r = __hip_atomic_fetch_add(&ctrl[XC_U(x)], 1u,
                                              __ATOMIC_RELAXED,
                                              __HIP_MEMORY_SCOPE_AGENT);
    ((unsigned*)BASE_)[0] = x;
    ((unsigned*)BASE_)[1] = r;
    // verification grid barrier: all claims posted
    __hip_atomic_fetch_add(&ctrl[IB0_U], 1u, __ATOMIC_RELAXED,
                           __HIP_MEMORY_SCOPE_AGENT);
    while (rload(&ctrl[IB0_U]) < NWG) __builtin_amdgcn_s_sleep(1);
    unsigned ok = 1u;
#pragma unroll
    for (int i = 0; i < 8; ++i) ok &= (rload(&ctrl[XC_U(i)]) == 32u);
    ((unsigned*)BASE_)[2] = ok;
  }
  __syncthreads();
  const bool fastx = (((unsigned*)BASE_)[2] != 0u);
  const int sl = fastx ? (int)((unsigned*)BASE_)[0] : ((int)blockIdx.x & 7);
  const int cw = fastx ? (int)((unsigned*)BASE_)[1] : ((int)blockIdx.x >> 3);
  __syncthreads();

  // ---- one-time LDS init from packed ws ----
  {
    const unsigned* s0 = (const unsigned*)(wsb + OFF_W0H) + cw * 4736;
    unsigned* d0 = (unsigned*)W0H_;
    for (int i = tid; i < 4736; i += TPB) d0[i] = s0[i];
    const unsigned* s1 = (const unsigned*)(wsb + OFF_W1AH) + cw * 4096;
    const unsigned* s2 = (const unsigned*)(wsb + OFF_W1AL) + cw * 4096;
    const unsigned* s3 = (const unsigned*)(wsb + OFF_W1BH) + cw * 4096;
    const unsigned* s4 = (const unsigned*)(wsb + OFF_W1BL) + cw * 4096;
    unsigned* d1 = (unsigned*)W1AH_; unsigned* d2 = (unsigned*)W1AL_;
    unsigned* d3 = (unsigned*)W1BH_; unsigned* d4 = (unsigned*)W1BL_;
    for (int i = tid; i < 4096; i += TPB) {
      const int c = i >> 7, d = i & 127;  // restride 128 -> 132 dwords
      d1[c * 132 + d] = s1[i];
      d2[c * 132 + d] = s2[i];
      d3[c * 132 + d] = s3[i];
      d4[c * 132 + d] = s4[i];
    }
    for (int i = tid; i < 2048; i += TPB)
      WLIN_[(i >> 8) * 260 + (i & 255)] = Wlin[i];
    if (tid < 32) {
      const int J = (tid >> 3) * 256 + cw * 8 + (tid & 7);
      B0_[tid] = bih0[J] + bhh0[J];
      B1_[tid] = bih1[J] + bhh1[J];
    }
    if (tid < 8) BLIN_[tid] = blin[tid];
    {  // permanent zero pad k=16..31 of AB
      const int r = tid >> 3, q = tid & 7;
      ((unsigned*)ABH_)[r * 148 + 8 + q] = 0u;
      ((unsigned*)ABL_)[r * 148 + 8 + q] = 0u;
    }
  }
  // grid barrier 1: everyone done READING overlay weight regions
  __syncthreads();
  if (tid == 0) {
    __hip_atomic_fetch_add(&ctrl[IB1_U], 1u, __ATOMIC_RELAXED,
                           __HIP_MEMORY_SCOPE_AGENT);
    while (rload(&ctrl[IB1_U]) < NWG) __builtin_amdgcn_s_sleep(1);
  }
  __syncthreads();
  // zero OWN (sl,cw) exchange ranges (both parities); scope-adaptive
  {
    const int b = sl * 8192 + cw * 256 + tid;
    x_store_u32(h0x + b, 0u, fastx);
    x_store_u32(h0x + 65536 + b, 0u, fastx);
    x_store_u32(h1x + b, 0u, fastx);
    x_store_u32(h1x + 65536 + b, 0u, fastx);
    vmdrain();
  }
  // grid barrier 2: zeroing visible before any exchange
  __syncthreads();
  if (tid == 0) {
    __hip_atomic_fetch_add(&ctrl[IB2_U], 1u, __ATOMIC_RELAXED,
                           __HIP_MEMORY_SCOPE_AGENT);
    while (rload(&ctrl[IB2_U]) < NWG) __builtin_amdgcn_s_sleep(1);
  }
  __syncthreads();

  // per-thread constants
  const int l = tid & 63, wv = tid >> 6;
  const int frow = ((wv >> 1) << 4) + (l & 15);
  const int fcol = ((wv & 1) << 4) + (l & 15);
  const int kg = (l >> 4) << 3;
  const int gr = ((wv >> 1) << 4) + ((l >> 4) << 2);
  const int rA = tid >> 3, uA = tid & 7;

  float c0s = 0.f, c1s = 0.f;

  for (int g = 0; g < 127; ++g) {
    const int s = (g - sl) & 7;
    const int t = g - s;
    if (t < 0 || t > 119) continue;
    const bool fresh = (s == 0);
    const int gb = g & 1;                            // buffer parity
    const unsigned tagv = 1u | (((unsigned)(g >> 1) & 1u) << 1);

    // ---- D: stage x -> AB[0..15] (colX MALL poll for feedback dims) ----
    {
      const int r = tid >> 3, dp = (tid & 7) << 1;
      unsigned hw, lw;
      if (t <= 7 && s < 8 - t) {
        const float* tp = traj + r * 2048 + (t + s) * 16 + dp;
        splitpack(tp[0], tp[1], hw, lw);
      } else if (dp < 8) {
        const int ti = (t <= 7) ? (2 * t + s - 1) : (t + s);
        const float* tp = traj + r * 2048 + ti * 16 + dp;
        splitpack(tp[0], tp[1], hw, lw);
      } else {
        const unsigned* cp = colx + (g - 8) * 256 + r * 8 + (dp - 8);
        unsigned w0, w1;
        do { mall_load2(cp, w0, w1); } while (!(w0 & 0x10000u) || !(w1 & 0x10000u));
        hw = (w0 & 0xffffu) | ((w1 & 0xffffu) << 16);
        lw = (w0 >> 16) | (w1 & 0xffff0000u);
        if (s == 7) {  // cache finisher base out[:,t-1]
          BASE_[r * 8 + dp - 8] = uf16(w0 & 0xffffu) + uf16(w0 >> 16);
          BASE_[r * 8 + dp - 7] = uf16(w1 & 0xffffu) + uf16(w1 >> 16);
        }
      }
      ((unsigned*)ABH_)[r * 148 + (dp >> 1)] = hw;
      ((unsigned*)ABL_)[r * 148 + (dp >> 1)] = lw;
    }
    __syncthreads();

    // ---- A+E: L0 gates = [x|0|h0] @ W0 + b0 ----
    f32x4 acc0;
    { const float b = B0_[fcol]; acc0 = (f32x4){b, b, b, b}; }
    if (!fresh) {
      for (int ks = 0; ks < 8; ++ks) {
        const f16x8 ah = *(const f16x8*)(ABH_ + frow * 296 + 32 + ks * 32 + kg);
        const f16x8 al = *(const f16x8*)(ABL_ + frow * 296 + 32 + ks * 32 + kg);
        const f16x8 wh = *(const f16x8*)(W0H_ + fcol * 296 + 32 + ks * 32 + kg);
        acc0 = mfma16(ah, wh, acc0);
        acc0 = mfma16(al, wh, acc0);
      }
    }
    {
      const f16x8 ah = *(const f16x8*)(ABH_ + frow * 296 + kg);
      const f16x8 al = *(const f16x8*)(ABL_ + frow * 296 + kg);
      const f16x8 wh = *(const f16x8*)(W0H_ + fcol * 296 + kg);
      acc0 = mfma16(ah, wh, acc0);
      acc0 = mfma16(al, wh, acc0);
#pragma unroll
      for (int q = 0; q < 4; ++q) GATES_[(gr + q) * 33 + fcol] = acc0[q];
    }
    __syncthreads();

    // ---- F: L0 act + h0X publish (scope-adaptive) ----
    {
      const float iv = GATES_[rA * 33 + uA];
      const float fv = GATES_[rA * 33 + 8 + uA];
      const float gv = GATES_[rA * 33 + 16 + uA];
      const float ov = GATES_[rA * 33 + 24 + uA];
      const float cold = fresh ? 0.f : c0s;
      const float cn = sigf(fv) * cold + sigf(iv) * tanhfast(gv);
      c0s = cn;
      const float hv = sigf(ov) * tanhfast(cn);
      const _Float16 hh = (_Float16)hv;
      unsigned lo = f16u((_Float16)(hv - (float)hh));
      lo = (lo & 0xFFFCu) | tagv;
      x_store_u32(h0x + gb * 65536 + sl * 8192 + rA * 256 + cw * 8 + uA,
                  f16u(hh) | (lo << 16), fastx);
      if (g == 126) {
        out[30720 + rA * 256 + cw * 8 + uA] = hv;   // h_n L0
        out[47104 + rA * 256 + cw * 8 + uA] = cn;   // c_n L0
      }
    }

    // ---- B': W1B*h1 (overlaps h0X store flight) ----
    f32x4 acc1;
    { const float b = B1_[fcol]; acc1 = (f32x4){b, b, b, b}; }
    if (!fresh) {
      for (int ks = 0; ks < 8; ++ks) {
        const f16x8 hh = *(const f16x8*)(H1H_ + frow * 264 + ks * 32 + kg);
        const f16x8 wh = *(const f16x8*)(W1BH_ + fcol * 264 + ks * 32 + kg);
        const f16x8 wl = *(const f16x8*)(W1BL_ + fcol * 264 + ks * 32 + kg);
        acc1 = mfma16(hh, wh, acc1);
        acc1 = mfma16(hh, wl, acc1);
      }
    }

    // ---- H: poll-gather h0X -> unpack into AB[32..287] ----
    {
      const int r = tid >> 3, c32 = (tid & 7) << 5;
      const unsigned* src = h0x + gb * 65536 + sl * 8192 + r * 256 + c32;
      f32x4 v0, v1, v2, v3, v4, v5, v6, v7;
      POLL8(src)
      unsigned* ah32 = (unsigned*)ABH_ + r * 148 + 16 + (c32 >> 1);
      unsigned* al32 = (unsigned*)ABL_ + r * 148 + 16 + (c32 >> 1);
      UNPK(v0, 0)  UNPK(v1, 2)  UNPK(v2, 4)  UNPK(v3, 6)
      UNPK(v4, 8)  UNPK(v5, 10) UNPK(v6, 12) UNPK(v7, 14)
    }
    __syncthreads();

    // ---- I: L1 W1A part (3 products), gates out ----
    {
      for (int ks = 0; ks < 8; ++ks) {
        const f16x8 ah = *(const f16x8*)(ABH_ + frow * 296 + 32 + ks * 32 + kg);
        const f16x8 al = *(const f16x8*)(ABL_ + frow * 296 + 32 + ks * 32 + kg);
        const f16x8 wh = *(const f16x8*)(W1AH_ + fcol * 264 + ks * 32 + kg);
        const f16x8 wl = *(const f16x8*)(W1AL_ + fcol * 264 + ks * 32 + kg);
        acc1 = mfma16(ah, wh, acc1);
        acc1 = mfma16(al, wh, acc1);
        acc1 = mfma16(ah, wl, acc1);
      }
#pragma unroll
      for (int q = 0; q < 4; ++q) GATES_[(gr + q) * 33 + fcol] = acc1[q];
    }
    __syncthreads();

    // ---- J: L1 act + h1X publish (scope-adaptive, unconditional) ----
    {
      const float iv = GATES_[rA * 33 + uA];
      const float fv = GATES_[rA * 33 + 8 + uA];
      const float gv = GATES_[rA * 33 + 16 + uA];
      const float ov = GATES_[rA * 33 + 24 + uA];
      const float cold = fresh ? 0.f : c1s;
      const float cn = sigf(fv) * cold + sigf(iv) * tanhfast(gv);
      c1s = cn;
      const float hv = sigf(ov) * tanhfast(cn);
      const _Float16 hh = (_Float16)hv;
      unsigned lo = f16u((_Float16)(hv - (float)hh));
      lo = (lo & 0xFFFCu) | tagv;
      x_store_u32(h1x + gb * 65536 + sl * 8192 + rA * 256 + cw * 8 + uA,
                  f16u(hh) | (lo << 16), fastx);
      if (g == 126) {
        out[38912 + rA * 256 + cw * 8 + uA] = hv;   // h_n L1
        out[55296 + rA * 256 + cw * 8 + uA] = cn;   // c_n L1
      }
    }

    // ---- L: poll-gather h1X -> H1H_ (s<7 all; s==7 only cw0 for head) ----
    if (s < 7 || cw == 0) {
      const int r = tid >> 3, c32 = (tid & 7) << 5;
      const unsigned* src = h1x + gb * 65536 + sl * 8192 + r * 256 + c32;
      f32x4 v0, v1, v2, v3, v4, v5, v6, v7;
      POLL8(src)
      unsigned* dst = (unsigned*)H1H_ + r * 132 + (c32 >> 1);
      PKH(v0, 0)  PKH(v1, 2)  PKH(v2, 4)  PKH(v3, 6)
      PKH(v4, 8)  PKH(v5, 10) PKH(v6, 12) PKH(v7, 14)
    }
    __syncthreads();

    // ---- head (finisher cw0 only): full 32x8 from own-gathered H1H_ ----
    if (s == 7 && cw == 0) {
      const int r = tid >> 3, o = tid & 7;
      const unsigned* hw = (const unsigned*)H1H_ + r * 132;
      const float* wp = WLIN_ + o * 260;
      float pred = BLIN_[o];
#pragma unroll 8
      for (int k = 0; k < 128; ++k) {
        const unsigned w = hw[k];
        pred = fmaf(uf16(w & 0xffffu), wp[2 * k], pred);
        pred = fmaf(uf16(w >> 16), wp[2 * k + 1], pred);
      }
      const float base = (t == 0) ? traj[r * 2048 + 7 * 16 + 8 + o]
                                  : BASE_[tid];
      const float v = base + pred;
      out[r * 960 + t * 8 + o] = v;               // exact f32 result
      const _Float16 hh = (_Float16)v;            // tagged mirror for feedback
      unsigned lo = f16u((_Float16)(v - (float)hh));
      lo = (lo & 0xFFFEu) | 1u;
      mall_store_u32(colx + t * 256 + tid, f16u(hh) | (lo << 16));
    }
  }
}

extern "C" void kernel_launch(void* const* d_in, const int* in_sizes, int n_in,
                              void* d_out, int out_size, void* d_ws, size_t ws_size,
                              hipStream_t stream) {
  (void)in_sizes; (void)n_in; (void)out_size; (void)ws_size;
  const float* traj = (const float*)d_in[0];
  const float* Wih0 = (const float*)d_in[1];
  const float* Whh0 = (const float*)d_in[2];
  const float* bih0 = (const float*)d_in[3];
  const float* bhh0 = (const float*)d_in[4];
  const float* Wih1 = (const float*)d_in[5];
  const float* Whh1 = (const float*)d_in[6];
  const float* bih1 = (const float*)d_in[7];
  const float* bhh1 = (const float*)d_in[8];
  const float* Wlin = (const float*)d_in[9];
  const float* blin = (const float*)d_in[10];
  float* out = (float*)d_out;
  char* wsb = (char*)d_ws;

  static bool attr_done = false;
  if (!attr_done) {
    (void)hipFuncSetAttribute((const void*)lstm_main,
                              hipFuncAttributeMaxDynamicSharedMemorySize,
                              SMEM_BYTES);
    attr_done = true;
  }

  hipMemsetAsync(d_ws, 0, CTRL_BYTES, stream);
  hipMemsetAsync(wsb + OFF_COLX, 0, COLX_BYTES, stream);
  lstm_prep<<<1184, 256, 0, stream>>>(Wih0, Whh0, Wih1, Whh1, wsb);

  void* args[] = {(void*)&traj, (void*)&bih0, (void*)&bhh0, (void*)&bih1,
                  (void*)&bhh1, (void*)&Wlin, (void*)&blin, (void*)&out,
                  (void*)&wsb};
  hipLaunchCooperativeKernel((void*)lstm_main, dim3(NWG), dim3(TPB), args,
                             SMEM_BYTES, stream);
}

// Round 6
// 1683.282 us; speedup vs baseline: 95.7108x; 95.7108x over previous
//
#include <hip/hip_runtime.h>

// OR_LSTM Round 14: proven-MALL primitives + latency-hiding pipeline reorder.
// B=32,T=128,D=16,H=256,WS=8,OUT=8. 127 iterations, 8-slot window pipeline,
// 256 wgs = 8 slots x 32 col-groups, TPB=256, 1 wg/CU (LDS-forced).
// R5 post-mortem: sc0-only LOADS hit stale L1 (refuted; 1024-spin escalation
// = 161ms). R14 reverts ALL exchange ops to the R11-proven sc0 sc1 (MALL)
// and ships the chain restructure alone:
//  - A (L0 h0-part, 16 MFMA) BEFORE the colX poll -> hides ~half colX RT.
//  - h1X poll moved from end of iter g to iter g+1 right before W1B (its
//    only consumer), after the h0X store -> h1X RT spans barrier+A+D+E+F
//    of the next iteration (fully hidden); h0X RT partially hidden by L'+B'.
//  - Finisher (s==7, cw==0) polls own-iteration h1X for the head, writes
//    out + tagged colX mirror. Exposed RTs/iter: ~0.5 colX + ~0.7 h0X +
//    finisher tail.

#define NWG 256
#define TPB 256

typedef float f32x4 __attribute__((ext_vector_type(4)));
typedef _Float16 f16x8 __attribute__((ext_vector_type(8)));
typedef unsigned u32x2 __attribute__((ext_vector_type(2)));

// ---- workspace byte layout ----
#define CTRL_BYTES 4096
#define OFF_W0H   36864      // f16 [1024 cols][296]   (init-only source)
#define OFF_W1AH  643072     // f16 [1024][256]        (init-only source)
#define OFF_W1AL  1167360
#define OFF_W1BH  1691648
#define OFF_W1BL  2215936
// overlays (live after init grid barriers; zeroed in-kernel between them):
#define OFF_H0X   OFF_W1AH   // u32 [2 par][8 sl][32 r][256 u] {hi16,lo16+tag}
#define OFF_H1X   OFF_W1AL   // u32 [2 par][8 sl][32 r][256 u] {hi16,lo16+tag}
// never-written-by-prep region (zeroed by memsetAsync):
#define OFF_COLX  2740224    // u32 [120 t][32 r][8 o]  {hi16, lo16|bit0}
#define COLX_BYTES 122880

// ---- ctrl u32 indices ----
#define IB1_U 32             // weights-read-done barrier
#define IB2_U 48             // zeroing-done barrier

// ---- dynamic LDS byte layout (<= 160KB) ----
#define L_W0H   0        // f16 [32][296]
#define L_W1AH  18944    // f16 [32][264]
#define L_W1AL  35840
#define L_W1BH  52736
#define L_W1BL  69632
#define L_ABH   86528    // f16 [32 rows][296]: x(0..15)|zero(16..31)|h0(32..287)
#define L_ABL   105472
#define L_H1H   124416   // f16 [32][264]
#define L_GATES 141312   // f32 [32][33]
#define L_WLIN  145536   // f32 [8][260]
#define L_BASE  155008   // f32 [32][8]
#define L_B0    156032
#define L_B1    156160
#define L_BLIN  156288
#define SMEM_BYTES 156320

__device__ __forceinline__ float sigf(float x) { return 1.0f / (1.0f + __expf(-x)); }
__device__ __forceinline__ float tanhfast(float x) {
  float e = __expf(2.0f * x);
  return 1.0f - 2.0f / (e + 1.0f);
}
__device__ __forceinline__ unsigned f16u(_Float16 h) {
  union { _Float16 h; unsigned short u; } c; c.h = h; return c.u;
}
__device__ __forceinline__ float uf16(unsigned u) {
  union { unsigned short s; _Float16 h; } c; c.s = (unsigned short)u; return (float)c.h;
}
__device__ __forceinline__ unsigned fbits(float x) {
  union { float f; unsigned u; } c; c.f = x; return c.u;
}
__device__ __forceinline__ void splitpack(float x0, float x1, unsigned& hw, unsigned& lw) {
  const _Float16 a = (_Float16)x0, b = (_Float16)x1;
  hw = f16u(a) | (f16u(b) << 16);
  lw = f16u((_Float16)(x0 - (float)a)) | (f16u((_Float16)(x1 - (float)b)) << 16);
}

__device__ __forceinline__ unsigned rload(const unsigned* p) {
  return __hip_atomic_load(p, __ATOMIC_RELAXED, __HIP_MEMORY_SCOPE_AGENT);
}
// MALL (device-coherent) ops: sc0 sc1 -- the R6/R11-proven primitives.
__device__ __forceinline__ void mall_store_u32(unsigned* p, unsigned v) {
  asm volatile("global_store_dword %0, %1, off sc0 sc1" :: "v"(p), "v"(v) : "memory");
}
__device__ __forceinline__ void mall_load2(const void* p, unsigned& x, unsigned& y) {
  u32x2 v;
  asm volatile("global_load_dwordx2 %0, %1, off sc0 sc1\n\ts_waitcnt vmcnt(0)"
               : "=v"(v) : "v"(p) : "memory");
  x = v.x; y = v.y;
}
__device__ __forceinline__ void mall_load8x4(const void* p, f32x4& a0, f32x4& a1,
                                             f32x4& a2, f32x4& a3, f32x4& a4,
                                             f32x4& a5, f32x4& a6, f32x4& a7) {
  asm volatile(
      "global_load_dwordx4 %0, %8, off sc0 sc1\n\t"
      "global_load_dwordx4 %1, %8, off offset:16 sc0 sc1\n\t"
      "global_load_dwordx4 %2, %8, off offset:32 sc0 sc1\n\t"
      "global_load_dwordx4 %3, %8, off offset:48 sc0 sc1\n\t"
      "global_load_dwordx4 %4, %8, off offset:64 sc0 sc1\n\t"
      "global_load_dwordx4 %5, %8, off offset:80 sc0 sc1\n\t"
      "global_load_dwordx4 %6, %8, off offset:96 sc0 sc1\n\t"
      "global_load_dwordx4 %7, %8, off offset:112 sc0 sc1\n\t"
      "s_waitcnt vmcnt(0)"
      : "=&v"(a0), "=&v"(a1), "=&v"(a2), "=&v"(a3),
        "=&v"(a4), "=&v"(a5), "=&v"(a6), "=&v"(a7)
      : "v"(p) : "memory");
}
__device__ __forceinline__ void vmdrain() {
  asm volatile("s_waitcnt vmcnt(0)" ::: "memory");
}
__device__ __forceinline__ f32x4 mfma16(f16x8 a, f16x8 b, f32x4 c) {
  return __builtin_amdgcn_mfma_f32_16x16x32_f16(a, b, c, 0, 0, 0);
}

// tag checks: h0X/h1X words carry tag in bits 17:16 (TAG is a parameter)
#define TG4(vv, TAG) ((((fbits(vv.x) >> 16) & 3u) == (TAG)) & (((fbits(vv.y) >> 16) & 3u) == (TAG)) & \
                      (((fbits(vv.z) >> 16) & 3u) == (TAG)) & (((fbits(vv.w) >> 16) & 3u) == (TAG)))
#define UNPK(vv, i2) {                                              \
    const unsigned w0 = fbits(vv.x), w1 = fbits(vv.y);              \
    const unsigned w2 = fbits(vv.z), w3 = fbits(vv.w);              \
    ah32[(i2)]     = (w0 & 0xffffu) | (w1 << 16);                   \
    ah32[(i2) + 1] = (w2 & 0xffffu) | (w3 << 16);                   \
    al32[(i2)]     = (w0 >> 16) | (w1 & 0xffff0000u);               \
    al32[(i2) + 1] = (w2 >> 16) | (w3 & 0xffff0000u); }
#define PKH(vv, i2) {                                               \
    dst[(i2)]     = (fbits(vv.x) & 0xffffu) | ((fbits(vv.y) & 0xffffu) << 16); \
    dst[(i2) + 1] = (fbits(vv.z) & 0xffffu) | ((fbits(vv.w) & 0xffffu) << 16); }
#define POLL8(srcp, TAG)                                             \
  { while (true) {                                                   \
      mall_load8x4(srcp, v0, v1, v2, v3, v4, v5, v6, v7);            \
      const unsigned ok = TG4(v0,TAG) & TG4(v1,TAG) & TG4(v2,TAG) &  \
                          TG4(v3,TAG) & TG4(v4,TAG) & TG4(v5,TAG) &  \
                          TG4(v6,TAG) & TG4(v7,TAG);                 \
      if (ok) break;                                                 \
    } }

// ---- prep (unchanged): pack weights into frag-ready f16 planes ----
__global__ __launch_bounds__(256) void lstm_prep(
    const float* __restrict__ Wih0, const float* __restrict__ Whh0,
    const float* __restrict__ Wih1, const float* __restrict__ Whh1,
    char* __restrict__ wsb) {
  const int i = blockIdx.x * 256 + threadIdx.x;
  _Float16* W0H = (_Float16*)(wsb + OFF_W0H);
  _Float16* W1AH = (_Float16*)(wsb + OFF_W1AH);
  _Float16* W1AL = (_Float16*)(wsb + OFF_W1AL);
  _Float16* W1BH = (_Float16*)(wsb + OFF_W1BH);
  _Float16* W1BL = (_Float16*)(wsb + OFF_W1BL);
  if (i < 1024 * 296) {           // W0 hi-only
    const int cg = i / 296, k = i - cg * 296;
    const int cw = cg >> 5, c = cg & 31;
    const int J = (c >> 3) * 256 + cw * 8 + (c & 7);
    float w = 0.f;
    if (k < 16) w = Wih0[J * 16 + k];
    else if (k >= 32 && k < 288) w = Whh0[J * 256 + (k - 32)];
    W0H[i] = (_Float16)w;
  }
  if (i < 1024 * 256) {           // W1A/W1B hi+lo
    const int cg = i >> 8, k = i & 255;
    const int cw = cg >> 5, c = cg & 31;
    const int J = (c >> 3) * 256 + cw * 8 + (c & 7);
    const float wa = Wih1[J * 256 + k];
    _Float16 h = (_Float16)wa;
    W1AH[i] = h; W1AL[i] = (_Float16)(wa - (float)h);
    const float wb = Whh1[J * 256 + k];
    h = (_Float16)wb;
    W1BH[i] = h; W1BL[i] = (_Float16)(wb - (float)h);
  }
}

__global__ __launch_bounds__(TPB, 1) void lstm_main(
    const float* __restrict__ traj,
    const float* __restrict__ bih0, const float* __restrict__ bhh0,
    const float* __restrict__ bih1, const float* __restrict__ bhh1,
    const float* __restrict__ Wlin, const float* __restrict__ blin,
    float* __restrict__ out, char* __restrict__ wsb) {
  extern __shared__ char smem[];
  _Float16* const W0H_  = (_Float16*)(smem + L_W0H);
  _Float16* const W1AH_ = (_Float16*)(smem + L_W1AH);
  _Float16* const W1AL_ = (_Float16*)(smem + L_W1AL);
  _Float16* const W1BH_ = (_Float16*)(smem + L_W1BH);
  _Float16* const W1BL_ = (_Float16*)(smem + L_W1BL);
  _Float16* const ABH_  = (_Float16*)(smem + L_ABH);
  _Float16* const ABL_  = (_Float16*)(smem + L_ABL);
  _Float16* const H1H_  = (_Float16*)(smem + L_H1H);
  float* const GATES_ = (float*)(smem + L_GATES);
  float* const WLIN_  = (float*)(smem + L_WLIN);
  float* const BASE_  = (float*)(smem + L_BASE);
  float* const B0_    = (float*)(smem + L_B0);
  float* const B1_    = (float*)(smem + L_B1);
  float* const BLIN_  = (float*)(smem + L_BLIN);

  const int tid = threadIdx.x;
  const int wg = blockIdx.x;
  const int sl = wg & 7;           // pipeline slot
  const int cw = wg >> 3;          // col-group: units [cw*8, cw*8+8)
  unsigned* ctrl = (unsigned*)wsb;
  unsigned* const h0x = (unsigned*)(wsb + OFF_H0X);
  unsigned* const h1x = (unsigned*)(wsb + OFF_H1X);
  unsigned* const colx = (unsigned*)(wsb + OFF_COLX);

  // ---- one-time LDS init from packed ws ----
  {
    const unsigned* s0 = (const unsigned*)(wsb + OFF_W0H) + cw * 4736;
    unsigned* d0 = (unsigned*)W0H_;
    for (int i = tid; i < 4736; i += TPB) d0[i] = s0[i];
    const unsigned* s1 = (const unsigned*)(wsb + OFF_W1AH) + cw * 4096;
    const unsigned* s2 = (const unsigned*)(wsb + OFF_W1AL) + cw * 4096;
    const unsigned* s3 = (const unsigned*)(wsb + OFF_W1BH) + cw * 4096;
    const unsigned* s4 = (const unsigned*)(wsb + OFF_W1BL) + cw * 4096;
    unsigned* d1 = (unsigned*)W1AH_; unsigned* d2 = (unsigned*)W1AL_;
    unsigned* d3 = (unsigned*)W1BH_; unsigned* d4 = (unsigned*)W1BL_;
    for (int i = tid; i < 4096; i += TPB) {
      const int c = i >> 7, d = i & 127;  // restride 128 -> 132 dwords
      d1[c * 132 + d] = s1[i];
      d2[c * 132 + d] = s2[i];
      d3[c * 132 + d] = s3[i];
      d4[c * 132 + d] = s4[i];
    }
    for (int i = tid; i < 2048; i += TPB)
      WLIN_[(i >> 8) * 260 + (i & 255)] = Wlin[i];
    if (tid < 32) {
      const int J = (tid >> 3) * 256 + cw * 8 + (tid & 7);
      B0_[tid] = bih0[J] + bhh0[J];
      B1_[tid] = bih1[J] + bhh1[J];
    }
    if (tid < 8) BLIN_[tid] = blin[tid];
    {  // permanent zero pad k=16..31 of AB
      const int r = tid >> 3, q = tid & 7;
      ((unsigned*)ABH_)[r * 148 + 8 + q] = 0u;
      ((unsigned*)ABL_)[r * 148 + 8 + q] = 0u;
    }
  }
  // grid barrier 1: everyone done READING overlay weight regions
  __syncthreads();
  if (tid == 0) {
    __hip_atomic_fetch_add(&ctrl[IB1_U], 1u, __ATOMIC_RELAXED,
                           __HIP_MEMORY_SCOPE_AGENT);
    while (rload(&ctrl[IB1_U]) < NWG) __builtin_amdgcn_s_sleep(1);
  }
  __syncthreads();
  // zero OWN (sl,cw) exchange ranges (both parities)
  {
    const int b = sl * 8192 + cw * 256 + tid;
    mall_store_u32(h0x + b, 0u);
    mall_store_u32(h0x + 65536 + b, 0u);
    mall_store_u32(h1x + b, 0u);
    mall_store_u32(h1x + 65536 + b, 0u);
    vmdrain();
  }
  // grid barrier 2: zeroing visible before any exchange
  __syncthreads();
  if (tid == 0) {
    __hip_atomic_fetch_add(&ctrl[IB2_U], 1u, __ATOMIC_RELAXED,
                           __HIP_MEMORY_SCOPE_AGENT);
    while (rload(&ctrl[IB2_U]) < NWG) __builtin_amdgcn_s_sleep(1);
  }
  __syncthreads();

  // per-thread constants
  const int l = tid & 63, wv = tid >> 6;
  const int frow = ((wv >> 1) << 4) + (l & 15);
  const int fcol = ((wv & 1) << 4) + (l & 15);
  const int kg = (l >> 4) << 3;
  const int gr = ((wv >> 1) << 4) + ((l >> 4) << 2);
  const int rA = tid >> 3, uA = tid & 7;

  float c0s = 0.f, c1s = 0.f;

  for (int g = 0; g < 127; ++g) {
    const int s = (g - sl) & 7;
    const int t = g - s;
    if (t < 0 || t > 119) continue;
    const bool fresh = (s == 0);
    const int gb = g & 1;                                   // buffer parity
    const unsigned tagv = 1u | (((unsigned)(g >> 1) & 1u) << 1);
    const int gbp = (g - 1) & 1;                            // prev parity
    const unsigned tagp = 1u | (((unsigned)((g - 1) >> 1) & 1u) << 1);

    // ---- A: L0 h0-part (16 MFMA, pre-column; hides colX RT) ----
    f32x4 acc0;
    { const float b = B0_[fcol]; acc0 = (f32x4){b, b, b, b}; }
    if (!fresh) {
      for (int ks = 0; ks < 8; ++ks) {
        const f16x8 ah = *(const f16x8*)(ABH_ + frow * 296 + 32 + ks * 32 + kg);
        const f16x8 al = *(const f16x8*)(ABL_ + frow * 296 + 32 + ks * 32 + kg);
        const f16x8 wh = *(const f16x8*)(W0H_ + fcol * 296 + 32 + ks * 32 + kg);
        acc0 = mfma16(ah, wh, acc0);
        acc0 = mfma16(al, wh, acc0);
      }
    }

    // ---- D: stage x -> AB[0..15] (colX MALL poll for feedback dims) ----
    {
      const int r = tid >> 3, dp = (tid & 7) << 1;
      unsigned hw, lw;
      if (t <= 7 && s < 8 - t) {
        const float* tp = traj + r * 2048 + (t + s) * 16 + dp;
        splitpack(tp[0], tp[1], hw, lw);
      } else if (dp < 8) {
        const int ti = (t <= 7) ? (2 * t + s - 1) : (t + s);
        const float* tp = traj + r * 2048 + ti * 16 + dp;
        splitpack(tp[0], tp[1], hw, lw);
      } else {
        const unsigned* cp = colx + (g - 8) * 256 + r * 8 + (dp - 8);
        unsigned w0, w1;
        do { mall_load2(cp, w0, w1); } while (!(w0 & 0x10000u) || !(w1 & 0x10000u));
        hw = (w0 & 0xffffu) | ((w1 & 0xffffu) << 16);
        lw = (w0 >> 16) | (w1 & 0xffff0000u);
        if (s == 7) {  // cache finisher base out[:,t-1]
          BASE_[r * 8 + dp - 8] = uf16(w0 & 0xffffu) + uf16(w0 >> 16);
          BASE_[r * 8 + dp - 7] = uf16(w1 & 0xffffu) + uf16(w1 >> 16);
        }
      }
      ((unsigned*)ABH_)[r * 148 + (dp >> 1)] = hw;
      ((unsigned*)ABL_)[r * 148 + (dp >> 1)] = lw;
    }
    __syncthreads();

    // ---- E: L0 x k-step, gates out ----
    {
      const f16x8 ah = *(const f16x8*)(ABH_ + frow * 296 + kg);
      const f16x8 al = *(const f16x8*)(ABL_ + frow * 296 + kg);
      const f16x8 wh = *(const f16x8*)(W0H_ + fcol * 296 + kg);
      acc0 = mfma16(ah, wh, acc0);
      acc0 = mfma16(al, wh, acc0);
#pragma unroll
      for (int q = 0; q < 4; ++q) GATES_[(gr + q) * 33 + fcol] = acc0[q];
    }
    __syncthreads();

    // ---- F: L0 act + h0X store (tag g) ----
    {
      const float iv = GATES_[rA * 33 + uA];
      const float fv = GATES_[rA * 33 + 8 + uA];
      const float gv = GATES_[rA * 33 + 16 + uA];
      const float ov = GATES_[rA * 33 + 24 + uA];
      const float cold = fresh ? 0.f : c0s;
      const float cn = sigf(fv) * cold + sigf(iv) * tanhfast(gv);
      c0s = cn;
      const float hv = sigf(ov) * tanhfast(cn);
      const _Float16 hh = (_Float16)hv;
      unsigned lo = f16u((_Float16)(hv - (float)hh));
      lo = (lo & 0xFFFCu) | tagv;
      mall_store_u32(h0x + gb * 65536 + sl * 8192 + rA * 256 + cw * 8 + uA,
                     f16u(hh) | (lo << 16));
      if (g == 126) {
        out[30720 + rA * 256 + cw * 8 + uA] = hv;   // h_n L0
        out[47104 + rA * 256 + cw * 8 + uA] = cn;   // c_n L0
      }
    }

    // ---- L': poll h1X of g-1 (late poll: RT was hidden by A..F) ----
    if (!fresh) {
      const int r = tid >> 3, c32 = (tid & 7) << 5;
      const unsigned* src = h1x + gbp * 65536 + sl * 8192 + r * 256 + c32;
      f32x4 v0, v1, v2, v3, v4, v5, v6, v7;
      POLL8(src, tagp)
      unsigned* dst = (unsigned*)H1H_ + r * 132 + (c32 >> 1);
      PKH(v0, 0)  PKH(v1, 2)  PKH(v2, 4)  PKH(v3, 6)
      PKH(v4, 8)  PKH(v5, 10) PKH(v6, 12) PKH(v7, 14)
    }
    __syncthreads();

    // ---- B': W1B*h1 (16 MFMA; overlaps h0X RT) ----
    f32x4 acc1;
    { const float b = B1_[fcol]; acc1 = (f32x4){b, b, b, b}; }
    if (!fresh) {
      for (int ks = 0; ks < 8; ++ks) {
        const f16x8 hh = *(const f16x8*)(H1H_ + frow * 264 + ks * 32 + kg);
        const f16x8 wh = *(const f16x8*)(W1BH_ + fcol * 264 + ks * 32 + kg);
        const f16x8 wl = *(const f16x8*)(W1BL_ + fcol * 264 + ks * 32 + kg);
        acc1 = mfma16(hh, wh, acc1);
        acc1 = mfma16(hh, wl, acc1);
      }
    }

    // ---- H: poll-gather h0X (tag g) -> unpack into AB[32..287] ----
    {
      const int r = tid >> 3, c32 = (tid & 7) << 5;
      const unsigned* src = h0x + gb * 65536 + sl * 8192 + r * 256 + c32;
      f32x4 v0, v1, v2, v3, v4, v5, v6, v7;
      POLL8(src, tagv)
      unsigned* ah32 = (unsigned*)ABH_ + r * 148 + 16 + (c32 >> 1);
      unsigned* al32 = (unsigned*)ABL_ + r * 148 + 16 + (c32 >> 1);
      UNPK(v0, 0)  UNPK(v1, 2)  UNPK(v2, 4)  UNPK(v3, 6)
      UNPK(v4, 8)  UNPK(v5, 10) UNPK(v6, 12) UNPK(v7, 14)
    }
    __syncthreads();

    // ---- I: L1 W1A part (24 MFMA), gates out ----
    {
      for (int ks = 0; ks < 8; ++ks) {
        const f16x8 ah = *(const f16x8*)(ABH_ + frow * 296 + 32 + ks * 32 + kg);
        const f16x8 al = *(const f16x8*)(ABL_ + frow * 296 + 32 + ks * 32 + kg);
        const f16x8 wh = *(const f16x8*)(W1AH_ + fcol * 264 + ks * 32 + kg);
        const f16x8 wl = *(const f16x8*)(W1AL_ + fcol * 264 + ks * 32 + kg);
        acc1 = mfma16(ah, wh, acc1);
        acc1 = mfma16(al, wh, acc1);
        acc1 = mfma16(ah, wl, acc1);
      }
#pragma unroll
      for (int q = 0; q < 4; ++q) GATES_[(gr + q) * 33 + fcol] = acc1[q];
    }
    __syncthreads();

    // ---- J: L1 act + h1X store (tag g; consumed at g+1 and by finisher) ----
    {
      const float iv = GATES_[rA * 33 + uA];
      const float fv = GATES_[rA * 33 + 8 + uA];
      const float gv = GATES_[rA * 33 + 16 + uA];
      const float ov = GATES_[rA * 33 + 24 + uA];
      const float cold = fresh ? 0.f : c1s;
      const float cn = sigf(fv) * cold + sigf(iv) * tanhfast(gv);
      c1s = cn;
      const float hv = sigf(ov) * tanhfast(cn);
      const _Float16 hh = (_Float16)hv;
      unsigned lo = f16u((_Float16)(hv - (float)hh));
      lo = (lo & 0xFFFCu) | tagv;
      mall_store_u32(h1x + gb * 65536 + sl * 8192 + rA * 256 + cw * 8 + uA,
                     f16u(hh) | (lo << 16));
      if (g == 126) {
        out[38912 + rA * 256 + cw * 8 + uA] = hv;   // h_n L1
        out[55296 + rA * 256 + cw * 8 + uA] = cn;   // c_n L1
      }
    }

    // ---- finisher (s==7, cw==0): poll h1X(g), head, out + colX ----
    if (s == 7 && cw == 0) {
      {
        const int r = tid >> 3, c32 = (tid & 7) << 5;
        const unsigned* src = h1x + gb * 65536 + sl * 8192 + r * 256 + c32;
        f32x4 v0, v1, v2, v3, v4, v5, v6, v7;
        POLL8(src, tagv)
        unsigned* dst = (unsigned*)H1H_ + r * 132 + (c32 >> 1);
        PKH(v0, 0)  PKH(v1, 2)  PKH(v2, 4)  PKH(v3, 6)
        PKH(v4, 8)  PKH(v5, 10) PKH(v6, 12) PKH(v7, 14)
      }
      __syncthreads();
      const int r = tid >> 3, o = tid & 7;
      const unsigned* hw = (const unsigned*)H1H_ + r * 132;
      const float* wp = WLIN_ + o * 260;
      float pred = BLIN_[o];
#pragma unroll 8
      for (int k = 0; k < 128; ++k) {
        const unsigned w = hw[k];
        pred = fmaf(uf16(w & 0xffffu), wp[2 * k], pred);
        pred = fmaf(uf16(w >> 16), wp[2 * k + 1], pred);
      }
      const float base = (t == 0) ? traj[r * 2048 + 7 * 16 + 8 + o]
                                  : BASE_[tid];
      const float v = base + pred;
      out[r * 960 + t * 8 + o] = v;               // exact f32 result
      const _Float16 hh = (_Float16)v;            // tagged mirror for feedback
      unsigned lo = f16u((_Float16)(v - (float)hh));
      lo = (lo & 0xFFFEu) | 1u;
      mall_store_u32(colx + t * 256 + tid, f16u(hh) | (lo << 16));
    }
  }
}

extern "C" void kernel_launch(void* const* d_in, const int* in_sizes, int n_in,
                              void* d_out, int out_size, void* d_ws, size_t ws_size,
                              hipStream_t stream) {
  (void)in_sizes; (void)n_in; (void)out_size; (void)ws_size;
  const float* traj = (const float*)d_in[0];
  const float* Wih0 = (const float*)d_in[1];
  const float* Whh0 = (const float*)d_in[2];
  const float* bih0 = (const float*)d_in[3];
  const float* bhh0 = (const float*)d_in[4];
  const float* Wih1 = (const float*)d_in[5];
  const float* Whh1 = (const float*)d_in[6];
  const float* bih1 = (const float*)d_in[7];
  const float* bhh1 = (const float*)d_in[8];
  const float* Wlin = (const float*)d_in[9];
  const float* blin = (const float*)d_in[10];
  float* out = (float*)d_out;
  char* wsb = (char*)d_ws;

  static bool attr_done = false;
  if (!attr_done) {
    (void)hipFuncSetAttribute((const void*)lstm_main,
                              hipFuncAttributeMaxDynamicSharedMemorySize,
                              SMEM_BYTES);
    attr_done = true;
  }

  hipMemsetAsync(d_ws, 0, CTRL_BYTES, stream);
  hipMemsetAsync(wsb + OFF_COLX, 0, COLX_BYTES, stream);
  lstm_prep<<<1184, 256, 0, stream>>>(Wih0, Whh0, Wih1, Whh1, wsb);

  void* args[] = {(void*)&traj, (void*)&bih0, (void*)&bhh0, (void*)&bih1,
                  (void*)&bhh1, (void*)&Wlin, (void*)&blin, (void*)&out,
                  (void*)&wsb};
  hipLaunchCooperativeKernel((void*)lstm_main, dim3(NWG), dim3(TPB), args,
                             SMEM_BYTES, stream);
}

// Round 7
// 1556.595 us; speedup vs baseline: 103.5004x; 1.0814x over previous
//
#include <hip/hip_runtime.h>

// OR_LSTM Round 15: R11 base + DISTRIBUTED HEAD + consumer-side column
// reconstruction (colX and the finisher funnel deleted).
// B=32,T=128,D=16,H=256,WS=8,OUT=8. 127 iterations, 8-slot window pipeline,
// 256 wgs = 8 slots x 32 col-groups, TPB=256.
// R14 lesson: R11's critical cycle = D(colX poll) ... J + finisher funnel
// (PB poll -> head -> colX store) -> next D. R15 removes the funnel:
//  - finishing slot's 32 wgs each store TAGGED 8-unit head partials
//    (f16 hi/lo + 2-bit generation tag, ring of 16 t-slots) right after J;
//  - EVERY wg polls the 32 partials for its (r,o) each iteration (poll IS
//    the data, 1 RT), reduces locally, maintains the feedback column in
//    LDS: COL += blin + sum. All wgs compute identical f32 columns.
//  - out[:,t] = plain off-chain store by slot7/cw0; column 119 via one-time
//    epilogue poll. colX, BASE_, finisher tail: gone (-2 serial RTs/iter).
// Ring-16 tags (bit0=written, bit1=(t>>4)&1) make re-zeroing unnecessary;
// slot drift bounded <=~9 by the PB dependency chain itself (<16, safe).

#define NWG 256
#define TPB 256

typedef float f32x4 __attribute__((ext_vector_type(4)));
typedef _Float16 f16x8 __attribute__((ext_vector_type(8)));

// ---- workspace byte layout ----
#define CTRL_BYTES 4096
#define OFF_W0H   36864      // f16 [1024 cols][296]   (init-only source)
#define OFF_W1AH  643072     // f16 [1024][256]        (init-only source)
#define OFF_W1AL  1167360
#define OFF_W1BH  1691648
#define OFF_W1BL  2215936
// overlays (live after init grid barriers; zeroed in-kernel between them):
#define OFF_H0X   OFF_W1AH   // u32 [2 par][8 sl][32 r][256 u] {hi16,lo16+tag}
#define OFF_H1X   OFF_W1AL   // u32 [2 par][8 sl][32 r][256 u] {hi16,lo16+tag}
#define OFF_PBR   OFF_W1BH   // u32 [16 ring][256 (r*8+o)][32 cw] partials

// ---- ctrl u32 indices ----
#define IB1_U 32             // weights-read-done barrier
#define IB2_U 48             // zeroing-done barrier

// ---- dynamic LDS byte layout (<= 160KB) ----
#define L_W0H   0        // f16 [32][296]
#define L_W1AH  18944    // f16 [32][264]
#define L_W1AL  35840
#define L_W1BH  52736
#define L_W1BL  69632
#define L_ABH   86528    // f16 [32 rows][296]: x(0..15)|zero(16..31)|h0(32..287)
#define L_ABL   105472
#define L_H1H   124416   // f16 [32][264]
#define L_GATES 141312   // f32 [32][33]
#define L_WLIN  145536   // f32 [8][260]
#define L_HOWN  153856   // f32 [32][9]
#define L_COL   155008   // f32 [32][8]  maintained feedback column out[:,t]
#define L_B0    156032
#define L_B1    156160
#define L_BLIN  156288
#define SMEM_BYTES 156320

__device__ __forceinline__ float sigf(float x) { return 1.0f / (1.0f + __expf(-x)); }
__device__ __forceinline__ float tanhfast(float x) {
  float e = __expf(2.0f * x);
  return 1.0f - 2.0f / (e + 1.0f);
}
__device__ __forceinline__ unsigned f16u(_Float16 h) {
  union { _Float16 h; unsigned short u; } c; c.h = h; return c.u;
}
__device__ __forceinline__ float uf16(unsigned u) {
  union { unsigned short s; _Float16 h; } c; c.s = (unsigned short)u; return (float)c.h;
}
__device__ __forceinline__ unsigned fbits(float x) {
  union { float f; unsigned u; } c; c.f = x; return c.u;
}
__device__ __forceinline__ void splitpack(float x0, float x1, unsigned& hw, unsigned& lw) {
  const _Float16 a = (_Float16)x0, b = (_Float16)x1;
  hw = f16u(a) | (f16u(b) << 16);
  lw = f16u((_Float16)(x0 - (float)a)) | (f16u((_Float16)(x1 - (float)b)) << 16);
}

__device__ __forceinline__ unsigned rload(const unsigned* p) {
  return __hip_atomic_load(p, __ATOMIC_RELAXED, __HIP_MEMORY_SCOPE_AGENT);
}
// MALL (device-coherent) ops: sc0 sc1 -- the proven primitives.
__device__ __forceinline__ void mall_store_u32(unsigned* p, unsigned v) {
  asm volatile("global_store_dword %0, %1, off sc0 sc1" :: "v"(p), "v"(v) : "memory");
}
__device__ __forceinline__ void mall_load8x4(const void* p, f32x4& a0, f32x4& a1,
                                             f32x4& a2, f32x4& a3, f32x4& a4,
                                             f32x4& a5, f32x4& a6, f32x4& a7) {
  asm volatile(
      "global_load_dwordx4 %0, %8, off sc0 sc1\n\t"
      "global_load_dwordx4 %1, %8, off offset:16 sc0 sc1\n\t"
      "global_load_dwordx4 %2, %8, off offset:32 sc0 sc1\n\t"
      "global_load_dwordx4 %3, %8, off offset:48 sc0 sc1\n\t"
      "global_load_dwordx4 %4, %8, off offset:64 sc0 sc1\n\t"
      "global_load_dwordx4 %5, %8, off offset:80 sc0 sc1\n\t"
      "global_load_dwordx4 %6, %8, off offset:96 sc0 sc1\n\t"
      "global_load_dwordx4 %7, %8, off offset:112 sc0 sc1\n\t"
      "s_waitcnt vmcnt(0)"
      : "=&v"(a0), "=&v"(a1), "=&v"(a2), "=&v"(a3),
        "=&v"(a4), "=&v"(a5), "=&v"(a6), "=&v"(a7)
      : "v"(p) : "memory");
}
__device__ __forceinline__ void vmdrain() {
  asm volatile("s_waitcnt vmcnt(0)" ::: "memory");
}
__device__ __forceinline__ f32x4 mfma16(f16x8 a, f16x8 b, f32x4 c) {
  return __builtin_amdgcn_mfma_f32_16x16x32_f16(a, b, c, 0, 0, 0);
}
// partial-word reduce: val = hi + lo (tag bits 17:16 masked out of lo)
__device__ __forceinline__ float sum4w(const f32x4 vv) {
  return uf16(fbits(vv.x) & 0xffffu) + uf16((fbits(vv.x) >> 16) & 0xFFFCu)
       + uf16(fbits(vv.y) & 0xffffu) + uf16((fbits(vv.y) >> 16) & 0xFFFCu)
       + uf16(fbits(vv.z) & 0xffffu) + uf16((fbits(vv.z) >> 16) & 0xFFFCu)
       + uf16(fbits(vv.w) & 0xffffu) + uf16((fbits(vv.w) >> 16) & 0xFFFCu);
}

// tag checks: words carry tag in bits 17:16
#define TG4(vv, TAG) ((((fbits(vv.x) >> 16) & 3u) == (TAG)) & (((fbits(vv.y) >> 16) & 3u) == (TAG)) & \
                      (((fbits(vv.z) >> 16) & 3u) == (TAG)) & (((fbits(vv.w) >> 16) & 3u) == (TAG)))
#define UNPK(vv, i2) {                                              \
    const unsigned w0 = fbits(vv.x), w1 = fbits(vv.y);              \
    const unsigned w2 = fbits(vv.z), w3 = fbits(vv.w);              \
    ah32[(i2)]     = (w0 & 0xffffu) | (w1 << 16);                   \
    ah32[(i2) + 1] = (w2 & 0xffffu) | (w3 << 16);                   \
    al32[(i2)]     = (w0 >> 16) | (w1 & 0xffff0000u);               \
    al32[(i2) + 1] = (w2 >> 16) | (w3 & 0xffff0000u); }
#define PKH(vv, i2) {                                               \
    dst[(i2)]     = (fbits(vv.x) & 0xffffu) | ((fbits(vv.y) & 0xffffu) << 16); \
    dst[(i2) + 1] = (fbits(vv.z) & 0xffffu) | ((fbits(vv.w) & 0xffffu) << 16); }
#define POLL8(srcp, TAG)                                             \
  { while (true) {                                                   \
      mall_load8x4(srcp, v0, v1, v2, v3, v4, v5, v6, v7);            \
      const unsigned ok = TG4(v0,TAG) & TG4(v1,TAG) & TG4(v2,TAG) &  \
                          TG4(v3,TAG) & TG4(v4,TAG) & TG4(v5,TAG) &  \
                          TG4(v6,TAG) & TG4(v7,TAG);                 \
      if (ok) break;                                                 \
    } }

// ---- prep (unchanged): pack weights into frag-ready f16 planes ----
__global__ __launch_bounds__(256) void lstm_prep(
    const float* __restrict__ Wih0, const float* __restrict__ Whh0,
    const float* __restrict__ Wih1, const float* __restrict__ Whh1,
    char* __restrict__ wsb) {
  const int i = blockIdx.x * 256 + threadIdx.x;
  _Float16* W0H = (_Float16*)(wsb + OFF_W0H);
  _Float16* W1AH = (_Float16*)(wsb + OFF_W1AH);
  _Float16* W1AL = (_Float16*)(wsb + OFF_W1AL);
  _Float16* W1BH = (_Float16*)(wsb + OFF_W1BH);
  _Float16* W1BL = (_Float16*)(wsb + OFF_W1BL);
  if (i < 1024 * 296) {           // W0 hi-only
    const int cg = i / 296, k = i - cg * 296;
    const int cw = cg >> 5, c = cg & 31;
    const int J = (c >> 3) * 256 + cw * 8 + (c & 7);
    float w = 0.f;
    if (k < 16) w = Wih0[J * 16 + k];
    else if (k >= 32 && k < 288) w = Whh0[J * 256 + (k - 32)];
    W0H[i] = (_Float16)w;
  }
  if (i < 1024 * 256) {           // W1A/W1B hi+lo
    const int cg = i >> 8, k = i & 255;
    const int cw = cg >> 5, c = cg & 31;
    const int J = (c >> 3) * 256 + cw * 8 + (c & 7);
    const float wa = Wih1[J * 256 + k];
    _Float16 h = (_Float16)wa;
    W1AH[i] = h; W1AL[i] = (_Float16)(wa - (float)h);
    const float wb = Whh1[J * 256 + k];
    h = (_Float16)wb;
    W1BH[i] = h; W1BL[i] = (_Float16)(wb - (float)h);
  }
}

__global__ __launch_bounds__(TPB, 1) void lstm_main(
    const float* __restrict__ traj,
    const float* __restrict__ bih0, const float* __restrict__ bhh0,
    const float* __restrict__ bih1, const float* __restrict__ bhh1,
    const float* __restrict__ Wlin, const float* __restrict__ blin,
    float* __restrict__ out, char* __restrict__ wsb) {
  extern __shared__ char smem[];
  _Float16* const W0H_  = (_Float16*)(smem + L_W0H);
  _Float16* const W1AH_ = (_Float16*)(smem + L_W1AH);
  _Float16* const W1AL_ = (_Float16*)(smem + L_W1AL);
  _Float16* const W1BH_ = (_Float16*)(smem + L_W1BH);
  _Float16* const W1BL_ = (_Float16*)(smem + L_W1BL);
  _Float16* const ABH_  = (_Float16*)(smem + L_ABH);
  _Float16* const ABL_  = (_Float16*)(smem + L_ABL);
  _Float16* const H1H_  = (_Float16*)(smem + L_H1H);
  float* const GATES_ = (float*)(smem + L_GATES);
  float* const WLIN_  = (float*)(smem + L_WLIN);
  float* const HOWN_  = (float*)(smem + L_HOWN);
  float* const COL_   = (float*)(smem + L_COL);
  float* const B0_    = (float*)(smem + L_B0);
  float* const B1_    = (float*)(smem + L_B1);
  float* const BLIN_  = (float*)(smem + L_BLIN);

  const int tid = threadIdx.x;
  const int wg = blockIdx.x;
  const int sl = wg & 7;           // pipeline slot
  const int cw = wg >> 3;          // col-group: units [cw*8, cw*8+8)
  unsigned* ctrl = (unsigned*)wsb;
  unsigned* const h0x = (unsigned*)(wsb + OFF_H0X);
  unsigned* const h1x = (unsigned*)(wsb + OFF_H1X);
  unsigned* const pbr = (unsigned*)(wsb + OFF_PBR);

  // ---- one-time LDS init from packed ws ----
  {
    const unsigned* s0 = (const unsigned*)(wsb + OFF_W0H) + cw * 4736;
    unsigned* d0 = (unsigned*)W0H_;
    for (int i = tid; i < 4736; i += TPB) d0[i] = s0[i];
    const unsigned* s1 = (const unsigned*)(wsb + OFF_W1AH) + cw * 4096;
    const unsigned* s2 = (const unsigned*)(wsb + OFF_W1AL) + cw * 4096;
    const unsigned* s3 = (const unsigned*)(wsb + OFF_W1BH) + cw * 4096;
    const unsigned* s4 = (const unsigned*)(wsb + OFF_W1BL) + cw * 4096;
    unsigned* d1 = (unsigned*)W1AH_; unsigned* d2 = (unsigned*)W1AL_;
    unsigned* d3 = (unsigned*)W1BH_; unsigned* d4 = (unsigned*)W1BL_;
    for (int i = tid; i < 4096; i += TPB) {
      const int c = i >> 7, d = i & 127;  // restride 128 -> 132 dwords
      d1[c * 132 + d] = s1[i];
      d2[c * 132 + d] = s2[i];
      d3[c * 132 + d] = s3[i];
      d4[c * 132 + d] = s4[i];
    }
    for (int i = tid; i < 2048; i += TPB)
      WLIN_[(i >> 8) * 260 + (i & 255)] = Wlin[i];
    if (tid < 32) {
      const int J = (tid >> 3) * 256 + cw * 8 + (tid & 7);
      B0_[tid] = bih0[J] + bhh0[J];
      B1_[tid] = bih1[J] + bhh1[J];
    }
    if (tid < 8) BLIN_[tid] = blin[tid];
    // COL init: base for out[:,0] = traj[:, 7, 8:16]
    COL_[tid] = traj[(tid >> 3) * 2048 + 7 * 16 + 8 + (tid & 7)];
    {  // permanent zero pad k=16..31 of AB
      const int r = tid >> 3, q = tid & 7;
      ((unsigned*)ABH_)[r * 148 + 8 + q] = 0u;
      ((unsigned*)ABL_)[r * 148 + 8 + q] = 0u;
    }
  }
  // grid barrier 1: everyone done READING overlay weight regions
  __syncthreads();
  if (tid == 0) {
    __hip_atomic_fetch_add(&ctrl[IB1_U], 1u, __ATOMIC_RELAXED,
                           __HIP_MEMORY_SCOPE_AGENT);
    while (rload(&ctrl[IB1_U]) < NWG) __builtin_amdgcn_s_sleep(1);
  }
  __syncthreads();
  // zero OWN exchange ranges: h0X/h1X (both parities) + PB ring share (2KB/wg)
  {
    const int b = sl * 8192 + cw * 256 + tid;
    mall_store_u32(h0x + b, 0u);
    mall_store_u32(h0x + 65536 + b, 0u);
    mall_store_u32(h1x + b, 0u);
    mall_store_u32(h1x + 65536 + b, 0u);
    unsigned* z = pbr + wg * 512;
    for (int i = tid; i < 512; i += TPB) mall_store_u32(z + i, 0u);
    vmdrain();
  }
  // grid barrier 2: zeroing visible before any exchange
  __syncthreads();
  if (tid == 0) {
    __hip_atomic_fetch_add(&ctrl[IB2_U], 1u, __ATOMIC_RELAXED,
                           __HIP_MEMORY_SCOPE_AGENT);
    while (rload(&ctrl[IB2_U]) < NWG) __builtin_amdgcn_s_sleep(1);
  }
  __syncthreads();

  // per-thread constants
  const int l = tid & 63, wv = tid >> 6;
  const int frow = ((wv >> 1) << 4) + (l & 15);
  const int fcol = ((wv & 1) << 4) + (l & 15);
  const int kg = (l >> 4) << 3;
  const int gr = ((wv >> 1) << 4) + ((l >> 4) << 2);
  const int rA = tid >> 3, uA = tid & 7;

  float c0s = 0.f, c1s = 0.f;

  for (int g = 0; g < 127; ++g) {
    const int s = (g - sl) & 7;
    const int t = g - s;
    if (t < 0 || t > 119) continue;
    const bool fresh = (s == 0);
    const int gb = g & 1;                                   // buffer parity
    const unsigned tagv = 1u | (((unsigned)(g >> 1) & 1u) << 1);

    // ---- A: L0 h0-part (16 MFMA; runs while PB partials propagate) ----
    f32x4 acc0;
    { const float b = B0_[fcol]; acc0 = (f32x4){b, b, b, b}; }
    if (!fresh) {
      for (int ks = 0; ks < 8; ++ks) {
        const f16x8 ah = *(const f16x8*)(ABH_ + frow * 296 + 32 + ks * 32 + kg);
        const f16x8 al = *(const f16x8*)(ABL_ + frow * 296 + 32 + ks * 32 + kg);
        const f16x8 wh = *(const f16x8*)(W0H_ + fcol * 296 + 32 + ks * 32 + kg);
        acc0 = mfma16(ah, wh, acc0);
        acc0 = mfma16(al, wh, acc0);
      }
    }

    // ---- D0: PB poll -> COL update (every wg, g>=8); out write off-chain ----
    if (g >= 8) {
      const int tc = g - 8;
      const unsigned ptag = 1u | (((unsigned)(tc >> 4) & 1u) << 1);
      const unsigned* src = pbr + (tc & 15) * 8192 + tid * 32;
      f32x4 v0, v1, v2, v3, v4, v5, v6, v7;
      POLL8(src, ptag)
      const float sum = sum4w(v0) + sum4w(v1) + sum4w(v2) + sum4w(v3) +
                        sum4w(v4) + sum4w(v5) + sum4w(v6) + sum4w(v7);
      const float nc = COL_[tid] + BLIN_[uA] + sum;
      COL_[tid] = nc;
      if (sl == 7 && cw == 0) out[rA * 960 + tc * 8 + uA] = nc;
    }
    __syncthreads();

    // ---- D: stage x -> AB[0..15] (feedback dims from LDS COL_) ----
    {
      const int r = tid >> 3, dp = (tid & 7) << 1;
      unsigned hw, lw;
      if (t <= 7 && s < 8 - t) {
        const float* tp = traj + r * 2048 + (t + s) * 16 + dp;
        splitpack(tp[0], tp[1], hw, lw);
      } else if (dp < 8) {
        const int ti = (t <= 7) ? (2 * t + s - 1) : (t + s);
        const float* tp = traj + r * 2048 + ti * 16 + dp;
        splitpack(tp[0], tp[1], hw, lw);
      } else {
        splitpack(COL_[r * 8 + dp - 8], COL_[r * 8 + dp - 7], hw, lw);
      }
      ((unsigned*)ABH_)[r * 148 + (dp >> 1)] = hw;
      ((unsigned*)ABL_)[r * 148 + (dp >> 1)] = lw;
    }
    __syncthreads();

    // ---- E: L0 x k-step, gates out ----
    {
      const f16x8 ah = *(const f16x8*)(ABH_ + frow * 296 + kg);
      const f16x8 al = *(const f16x8*)(ABL_ + frow * 296 + kg);
      const f16x8 wh = *(const f16x8*)(W0H_ + fcol * 296 + kg);
      acc0 = mfma16(ah, wh, acc0);
      acc0 = mfma16(al, wh, acc0);
#pragma unroll
      for (int q = 0; q < 4; ++q) GATES_[(gr + q) * 33 + fcol] = acc0[q];
    }
    __syncthreads();

    // ---- F: L0 act + h0X store (tag g) ----
    {
      const float iv = GATES_[rA * 33 + uA];
      const float fv = GATES_[rA * 33 + 8 + uA];
      const float gv = GATES_[rA * 33 + 16 + uA];
      const float ov = GATES_[rA * 33 + 24 + uA];
      const float cold = fresh ? 0.f : c0s;
      const float cn = sigf(fv) * cold + sigf(iv) * tanhfast(gv);
      c0s = cn;
      const float hv = sigf(ov) * tanhfast(cn);
      const _Float16 hh = (_Float16)hv;
      unsigned lo = f16u((_Float16)(hv - (float)hh));
      lo = (lo & 0xFFFCu) | tagv;
      mall_store_u32(h0x + gb * 65536 + sl * 8192 + rA * 256 + cw * 8 + uA,
                     f16u(hh) | (lo << 16));
      if (g == 126) {
        out[30720 + rA * 256 + cw * 8 + uA] = hv;   // h_n L0
        out[47104 + rA * 256 + cw * 8 + uA] = cn;   // c_n L0
      }
    }

    // ---- B': W1B*h1 (16 MFMA, memory-quiet; hides h0X propagation) ----
    f32x4 acc1;
    { const float b = B1_[fcol]; acc1 = (f32x4){b, b, b, b}; }
    if (!fresh) {
      for (int ks = 0; ks < 8; ++ks) {
        const f16x8 hh = *(const f16x8*)(H1H_ + frow * 264 + ks * 32 + kg);
        const f16x8 wh = *(const f16x8*)(W1BH_ + fcol * 264 + ks * 32 + kg);
        const f16x8 wl = *(const f16x8*)(W1BL_ + fcol * 264 + ks * 32 + kg);
        acc1 = mfma16(hh, wh, acc1);
        acc1 = mfma16(hh, wl, acc1);
      }
    }

    // ---- H: poll-gather h0X (tag g) -> unpack into AB[32..287] ----
    {
      const int r = tid >> 3, c32 = (tid & 7) << 5;
      const unsigned* src = h0x + gb * 65536 + sl * 8192 + r * 256 + c32;
      f32x4 v0, v1, v2, v3, v4, v5, v6, v7;
      POLL8(src, tagv)
      unsigned* ah32 = (unsigned*)ABH_ + r * 148 + 16 + (c32 >> 1);
      unsigned* al32 = (unsigned*)ABL_ + r * 148 + 16 + (c32 >> 1);
      UNPK(v0, 0)  UNPK(v1, 2)  UNPK(v2, 4)  UNPK(v3, 6)
      UNPK(v4, 8)  UNPK(v5, 10) UNPK(v6, 12) UNPK(v7, 14)
    }
    __syncthreads();

    // ---- I: L1 W1A part (24 MFMA), gates out ----
    {
      for (int ks = 0; ks < 8; ++ks) {
        const f16x8 ah = *(const f16x8*)(ABH_ + frow * 296 + 32 + ks * 32 + kg);
        const f16x8 al = *(const f16x8*)(ABL_ + frow * 296 + 32 + ks * 32 + kg);
        const f16x8 wh = *(const f16x8*)(W1AH_ + fcol * 264 + ks * 32 + kg);
        const f16x8 wl = *(const f16x8*)(W1AL_ + fcol * 264 + ks * 32 + kg);
        acc1 = mfma16(ah, wh, acc1);
        acc1 = mfma16(al, wh, acc1);
        acc1 = mfma16(ah, wl, acc1);
      }
#pragma unroll
      for (int q = 0; q < 4; ++q) GATES_[(gr + q) * 33 + fcol] = acc1[q];
    }
    __syncthreads();

    // ---- J: L1 act; HOWN; h1X store (s<7 only) ----
    {
      const float iv = GATES_[rA * 33 + uA];
      const float fv = GATES_[rA * 33 + 8 + uA];
      const float gv = GATES_[rA * 33 + 16 + uA];
      const float ov = GATES_[rA * 33 + 24 + uA];
      const float cold = fresh ? 0.f : c1s;
      const float cn = sigf(fv) * cold + sigf(iv) * tanhfast(gv);
      c1s = cn;
      const float hv = sigf(ov) * tanhfast(cn);
      HOWN_[rA * 9 + uA] = hv;
      if (s < 7) {
        const _Float16 hh = (_Float16)hv;
        unsigned lo = f16u((_Float16)(hv - (float)hh));
        lo = (lo & 0xFFFCu) | tagv;
        mall_store_u32(h1x + gb * 65536 + sl * 8192 + rA * 256 + cw * 8 + uA,
                       f16u(hh) | (lo << 16));
      }
      if (g == 126) {
        out[38912 + rA * 256 + cw * 8 + uA] = hv;   // h_n L1
        out[55296 + rA * 256 + cw * 8 + uA] = cn;   // c_n L1
      }
    }
    __syncthreads();

    // ---- tail: finishing slot -> tagged head partials; others -> h1X gather ----
    if (s == 7) {
      // partials for column t (== g-7): 8-unit dot per (r,o), f16 hi/lo + tag
      const unsigned ptag = 1u | (((unsigned)(t >> 4) & 1u) << 1);
      const float* wl = WLIN_ + uA * 260 + cw * 8;
      const float* hb = HOWN_ + rA * 9;
      float p = 0.f;
#pragma unroll
      for (int u = 0; u < 8; ++u) p = fmaf(hb[u], wl[u], p);
      const _Float16 ph = (_Float16)p;
      unsigned lo = f16u((_Float16)(p - (float)ph));
      lo = (lo & 0xFFFCu) | ptag;
      mall_store_u32(pbr + (t & 15) * 8192 + tid * 32 + cw,
                     f16u(ph) | (lo << 16));
      // epilogue: column 119 consumed by nobody -> cw0 polls and writes it
      if (g == 126 && cw == 0) {
        const unsigned* src = pbr + (119 & 15) * 8192 + tid * 32;
        f32x4 v0, v1, v2, v3, v4, v5, v6, v7;
        POLL8(src, ptag)
        const float sum = sum4w(v0) + sum4w(v1) + sum4w(v2) + sum4w(v3) +
                          sum4w(v4) + sum4w(v5) + sum4w(v6) + sum4w(v7);
        out[rA * 960 + 119 * 8 + uA] = COL_[tid] + BLIN_[uA] + sum;
      }
    } else {
      const int r = tid >> 3, c32 = (tid & 7) << 5;
      const unsigned* src = h1x + gb * 65536 + sl * 8192 + r * 256 + c32;
      f32x4 v0, v1, v2, v3, v4, v5, v6, v7;
      POLL8(src, tagv)
      unsigned* dst = (unsigned*)H1H_ + r * 132 + (c32 >> 1);
      PKH(v0, 0)  PKH(v1, 2)  PKH(v2, 4)  PKH(v3, 6)
      PKH(v4, 8)  PKH(v5, 10) PKH(v6, 12) PKH(v7, 14)
    }
    __syncthreads();
  }
}

extern "C" void kernel_launch(void* const* d_in, const int* in_sizes, int n_in,
                              void* d_out, int out_size, void* d_ws, size_t ws_size,
                              hipStream_t stream) {
  (void)in_sizes; (void)n_in; (void)out_size; (void)ws_size;
  const float* traj = (const float*)d_in[0];
  const float* Wih0 = (const float*)d_in[1];
  const float* Whh0 = (const float*)d_in[2];
  const float* bih0 = (const float*)d_in[3];
  const float* bhh0 = (const float*)d_in[4];
  const float* Wih1 = (const float*)d_in[5];
  const float* Whh1 = (const float*)d_in[6];
  const float* bih1 = (const float*)d_in[7];
  const float* bhh1 = (const float*)d_in[8];
  const float* Wlin = (const float*)d_in[9];
  const float* blin = (const float*)d_in[10];
  float* out = (float*)d_out;
  char* wsb = (char*)d_ws;

  static bool attr_done = false;
  if (!attr_done) {
    (void)hipFuncSetAttribute((const void*)lstm_main,
                              hipFuncAttributeMaxDynamicSharedMemorySize,
                              SMEM_BYTES);
    attr_done = true;
  }

  hipMemsetAsync(d_ws, 0, CTRL_BYTES, stream);
  lstm_prep<<<1184, 256, 0, stream>>>(Wih0, Whh0, Wih1, Whh1, wsb);

  void* args[] = {(void*)&traj, (void*)&bih0, (void*)&bhh0, (void*)&bih1,
                  (void*)&bhh1, (void*)&Wlin, (void*)&blin, (void*)&out,
                  (void*)&wsb};
  hipLaunchCooperativeKernel((void*)lstm_main, dim3(NWG), dim3(TPB), args,
                             SMEM_BYTES, stream);
}

// Round 8
// 1367.024 us; speedup vs baseline: 117.8533x; 1.1387x over previous
//
#include <hip/hip_runtime.h>

// OR_LSTM Round 16: R11 base + h1X PREFETCH-AT-TOP (phase L deleted).
// B=32,T=128,D=16,H=256,WS=8,OUT=8. 127 iterations, 8-slot window pipeline,
// 256 wgs = 8 slots x 32 col-groups, TPB=256.
// Hop model (R10-R15 evidence): sc0sc1 store->poll visibility ~1.5us; read
// bursts inside a store->poll window inflate it (R14/R15 regressions).
// R11 cycle = colX(1.5) + h0X(1.3) + h1X-at-L(1.3, polls 0.2us-old data) +
// PB(1.5) + compute = 9.2us/iter. R16 deletes the h1X hop: loads for
// h1X(g-1) are ISSUED at iteration-g top (data ~7us old -> no spin) and
// complete for free under A-E; registers land in H1H_ just before F, so the
// F->H window stays memory-quiet (LDS + barrier + register MFMA only).
// Tag-verify + rare respin guards stragglers. s_sleep backoff on h0X/PB
// spins. Barriers 7 -> 5 (J-barrier only for the finishing slot).

#define NWG 256
#define TPB 256

typedef float f32x4 __attribute__((ext_vector_type(4)));
typedef _Float16 f16x8 __attribute__((ext_vector_type(8)));
typedef unsigned u32x2 __attribute__((ext_vector_type(2)));

// ---- workspace byte layout ----
#define CTRL_BYTES 4096
#define OFF_W0H   36864      // f16 [1024 cols][296]   (init-only source)
#define OFF_W1AH  643072     // f16 [1024][256]        (init-only source)
#define OFF_W1AL  1167360
#define OFF_W1BH  1691648
#define OFF_W1BL  2215936
// overlays (live after init grid barriers; zeroed in-kernel between them):
#define OFF_H0X   OFF_W1AH   // u32 [2 par][8 sl][32 r][256 u] {hi16,lo16+tag}
#define OFF_H1X   OFF_W1AL   // u32 [2 par][8 sl][32 r][256 u] {hi16,lo16+tag}
// never-written-by-prep region (zeroed by memsetAsync):
#define OFF_COLX  2740224    // u32 [120 t][32 r][8 o]  {hi16, lo16|bit0}
#define OFF_PB    2863104    // f32 [2 par][256 (r*8+o)][32 cw]  bits1:0=tag
#define PBCOLX_BYTES 188416  // 122880 + 65536

// ---- ctrl u32 indices ----
#define IB1_U 32             // weights-read-done barrier
#define IB2_U 48             // zeroing-done barrier

// ---- dynamic LDS byte layout (<= 160KB) ----
#define L_W0H   0        // f16 [32][296]
#define L_W1AH  18944    // f16 [32][264]
#define L_W1AL  35840
#define L_W1BH  52736
#define L_W1BL  69632
#define L_ABH   86528    // f16 [32 rows][296]: x(0..15)|zero(16..31)|h0(32..287)
#define L_ABL   105472
#define L_H1H   124416   // f16 [32][264]
#define L_GATES 141312   // f32 [32][33]
#define L_WLIN  145536   // f32 [8][260]
#define L_HOWN  153856   // f32 [32][9]
#define L_BASE  155008   // f32 [32][8]
#define L_B0    156032
#define L_B1    156160
#define L_BLIN  156288
#define SMEM_BYTES 156320

__device__ __forceinline__ float sigf(float x) { return 1.0f / (1.0f + __expf(-x)); }
__device__ __forceinline__ float tanhfast(float x) {
  float e = __expf(2.0f * x);
  return 1.0f - 2.0f / (e + 1.0f);
}
__device__ __forceinline__ unsigned f16u(_Float16 h) {
  union { _Float16 h; unsigned short u; } c; c.h = h; return c.u;
}
__device__ __forceinline__ float uf16(unsigned u) {
  union { unsigned short s; _Float16 h; } c; c.s = (unsigned short)u; return (float)c.h;
}
__device__ __forceinline__ unsigned fbits(float x) {
  union { float f; unsigned u; } c; c.f = x; return c.u;
}
__device__ __forceinline__ void splitpack(float x0, float x1, unsigned& hw, unsigned& lw) {
  const _Float16 a = (_Float16)x0, b = (_Float16)x1;
  hw = f16u(a) | (f16u(b) << 16);
  lw = f16u((_Float16)(x0 - (float)a)) | (f16u((_Float16)(x1 - (float)b)) << 16);
}

__device__ __forceinline__ unsigned rload(const unsigned* p) {
  return __hip_atomic_load(p, __ATOMIC_RELAXED, __HIP_MEMORY_SCOPE_AGENT);
}
// MALL (device-coherent) ops: sc0 sc1 -- the proven primitives.
__device__ __forceinline__ void mall_store_u32(unsigned* p, unsigned v) {
  asm volatile("global_store_dword %0, %1, off sc0 sc1" :: "v"(p), "v"(v) : "memory");
}
__device__ __forceinline__ void mall_load2(const void* p, unsigned& x, unsigned& y) {
  u32x2 v;
  asm volatile("global_load_dwordx2 %0, %1, off sc0 sc1\n\ts_waitcnt vmcnt(0)"
               : "=v"(v) : "v"(p) : "memory");
  x = v.x; y = v.y;
}
__device__ __forceinline__ void mall_load8x4(const void* p, f32x4& a0, f32x4& a1,
                                             f32x4& a2, f32x4& a3, f32x4& a4,
                                             f32x4& a5, f32x4& a6, f32x4& a7) {
  asm volatile(
      "global_load_dwordx4 %0, %8, off sc0 sc1\n\t"
      "global_load_dwordx4 %1, %8, off offset:16 sc0 sc1\n\t"
      "global_load_dwordx4 %2, %8, off offset:32 sc0 sc1\n\t"
      "global_load_dwordx4 %3, %8, off offset:48 sc0 sc1\n\t"
      "global_load_dwordx4 %4, %8, off offset:64 sc0 sc1\n\t"
      "global_load_dwordx4 %5, %8, off offset:80 sc0 sc1\n\t"
      "global_load_dwordx4 %6, %8, off offset:96 sc0 sc1\n\t"
      "global_load_dwordx4 %7, %8, off offset:112 sc0 sc1\n\t"
      "s_waitcnt vmcnt(0)"
      : "=&v"(a0), "=&v"(a1), "=&v"(a2), "=&v"(a3),
        "=&v"(a4), "=&v"(a5), "=&v"(a6), "=&v"(a7)
      : "v"(p) : "memory");
}
// fire-and-forget issue (NO waitcnt): for prefetching data known to be old.
__device__ __forceinline__ void mall_issue8x4(const void* p, f32x4& a0, f32x4& a1,
                                              f32x4& a2, f32x4& a3, f32x4& a4,
                                              f32x4& a5, f32x4& a6, f32x4& a7) {
  asm volatile(
      "global_load_dwordx4 %0, %8, off sc0 sc1\n\t"
      "global_load_dwordx4 %1, %8, off offset:16 sc0 sc1\n\t"
      "global_load_dwordx4 %2, %8, off offset:32 sc0 sc1\n\t"
      "global_load_dwordx4 %3, %8, off offset:48 sc0 sc1\n\t"
      "global_load_dwordx4 %4, %8, off offset:64 sc0 sc1\n\t"
      "global_load_dwordx4 %5, %8, off offset:80 sc0 sc1\n\t"
      "global_load_dwordx4 %6, %8, off offset:96 sc0 sc1\n\t"
      "global_load_dwordx4 %7, %8, off offset:112 sc0 sc1"
      : "=&v"(a0), "=&v"(a1), "=&v"(a2), "=&v"(a3),
        "=&v"(a4), "=&v"(a5), "=&v"(a6), "=&v"(a7)
      : "v"(p) : "memory");
}
__device__ __forceinline__ void vmdrain() {
  asm volatile("s_waitcnt vmcnt(0)" ::: "memory");
}
__device__ __forceinline__ f32x4 mfma16(f16x8 a, f16x8 b, f32x4 c) {
  return __builtin_amdgcn_mfma_f32_16x16x32_f16(a, b, c, 0, 0, 0);
}

// tag checks: h0X/h1X words carry tag in bits 17:16; PB f32 in bits 1:0.
#define TG4(vv, TAG) ((((fbits(vv.x) >> 16) & 3u) == (TAG)) & (((fbits(vv.y) >> 16) & 3u) == (TAG)) & \
                      (((fbits(vv.z) >> 16) & 3u) == (TAG)) & (((fbits(vv.w) >> 16) & 3u) == (TAG)))
#define TP4(vv, TAG) (((fbits(vv.x) & 3u) == (TAG)) & ((fbits(vv.y) & 3u) == (TAG)) & \
                      ((fbits(vv.z) & 3u) == (TAG)) & ((fbits(vv.w) & 3u) == (TAG)))
#define UNPK(vv, i2) {                                              \
    const unsigned w0 = fbits(vv.x), w1 = fbits(vv.y);              \
    const unsigned w2 = fbits(vv.z), w3 = fbits(vv.w);              \
    ah32[(i2)]     = (w0 & 0xffffu) | (w1 << 16);                   \
    ah32[(i2) + 1] = (w2 & 0xffffu) | (w3 << 16);                   \
    al32[(i2)]     = (w0 >> 16) | (w1 & 0xffff0000u);               \
    al32[(i2) + 1] = (w2 >> 16) | (w3 & 0xffff0000u); }
#define PKH(vv, i2) {                                               \
    dst[(i2)]     = (fbits(vv.x) & 0xffffu) | ((fbits(vv.y) & 0xffffu) << 16); \
    dst[(i2) + 1] = (fbits(vv.z) & 0xffffu) | ((fbits(vv.w) & 0xffffu) << 16); }
// spin-poll with s_sleep backoff (reduces MALL interference while waiting)
#define POLL8(srcp, TAG)                                             \
  { int fails = 0;                                                   \
    while (true) {                                                   \
      mall_load8x4(srcp, v0, v1, v2, v3, v4, v5, v6, v7);            \
      const unsigned ok = TG4(v0,TAG) & TG4(v1,TAG) & TG4(v2,TAG) &  \
                          TG4(v3,TAG) & TG4(v4,TAG) & TG4(v5,TAG) &  \
                          TG4(v6,TAG) & TG4(v7,TAG);                 \
      if (ok) break;                                                 \
      if (++fails > 1) __builtin_amdgcn_s_sleep(1);                  \
    } }
#define POLLPB(srcp, TAG)                                            \
  { int fails = 0;                                                   \
    while (true) {                                                   \
      mall_load8x4(srcp, v0, v1, v2, v3, v4, v5, v6, v7);            \
      const unsigned ok = TP4(v0,TAG) & TP4(v1,TAG) & TP4(v2,TAG) &  \
                          TP4(v3,TAG) & TP4(v4,TAG) & TP4(v5,TAG) &  \
                          TP4(v6,TAG) & TP4(v7,TAG);                 \
      if (ok) break;                                                 \
      if (++fails > 1) __builtin_amdgcn_s_sleep(1);                  \
    } }

// ---- prep (unchanged): pack weights into frag-ready f16 planes ----
__global__ __launch_bounds__(256) void lstm_prep(
    const float* __restrict__ Wih0, const float* __restrict__ Whh0,
    const float* __restrict__ Wih1, const float* __restrict__ Whh1,
    char* __restrict__ wsb) {
  const int i = blockIdx.x * 256 + threadIdx.x;
  _Float16* W0H = (_Float16*)(wsb + OFF_W0H);
  _Float16* W1AH = (_Float16*)(wsb + OFF_W1AH);
  _Float16* W1AL = (_Float16*)(wsb + OFF_W1AL);
  _Float16* W1BH = (_Float16*)(wsb + OFF_W1BH);
  _Float16* W1BL = (_Float16*)(wsb + OFF_W1BL);
  if (i < 1024 * 296) {           // W0 hi-only
    const int cg = i / 296, k = i - cg * 296;
    const int cw = cg >> 5, c = cg & 31;
    const int J = (c >> 3) * 256 + cw * 8 + (c & 7);
    float w = 0.f;
    if (k < 16) w = Wih0[J * 16 + k];
    else if (k >= 32 && k < 288) w = Whh0[J * 256 + (k - 32)];
    W0H[i] = (_Float16)w;
  }
  if (i < 1024 * 256) {           // W1A/W1B hi+lo
    const int cg = i >> 8, k = i & 255;
    const int cw = cg >> 5, c = cg & 31;
    const int J = (c >> 3) * 256 + cw * 8 + (c & 7);
    const float wa = Wih1[J * 256 + k];
    _Float16 h = (_Float16)wa;
    W1AH[i] = h; W1AL[i] = (_Float16)(wa - (float)h);
    const float wb = Whh1[J * 256 + k];
    h = (_Float16)wb;
    W1BH[i] = h; W1BL[i] = (_Float16)(wb - (float)h);
  }
}

__global__ __launch_bounds__(TPB, 1) void lstm_main(
    const float* __restrict__ traj,
    const float* __restrict__ bih0, const float* __restrict__ bhh0,
    const float* __restrict__ bih1, const float* __restrict__ bhh1,
    const float* __restrict__ Wlin, const float* __restrict__ blin,
    float* __restrict__ out, char* __restrict__ wsb) {
  extern __shared__ char smem[];
  _Float16* const W0H_  = (_Float16*)(smem + L_W0H);
  _Float16* const W1AH_ = (_Float16*)(smem + L_W1AH);
  _Float16* const W1AL_ = (_Float16*)(smem + L_W1AL);
  _Float16* const W1BH_ = (_Float16*)(smem + L_W1BH);
  _Float16* const W1BL_ = (_Float16*)(smem + L_W1BL);
  _Float16* const ABH_  = (_Float16*)(smem + L_ABH);
  _Float16* const ABL_  = (_Float16*)(smem + L_ABL);
  _Float16* const H1H_  = (_Float16*)(smem + L_H1H);
  float* const GATES_ = (float*)(smem + L_GATES);
  float* const WLIN_  = (float*)(smem + L_WLIN);
  float* const HOWN_  = (float*)(smem + L_HOWN);
  float* const BASE_  = (float*)(smem + L_BASE);
  float* const B0_    = (float*)(smem + L_B0);
  float* const B1_    = (float*)(smem + L_B1);
  float* const BLIN_  = (float*)(smem + L_BLIN);

  const int tid = threadIdx.x;
  const int wg = blockIdx.x;
  const int sl = wg & 7;           // pipeline slot
  const int cw = wg >> 3;          // col-group: units [cw*8, cw*8+8)
  unsigned* ctrl = (unsigned*)wsb;
  unsigned* const h0x = (unsigned*)(wsb + OFF_H0X);
  unsigned* const h1x = (unsigned*)(wsb + OFF_H1X);
  unsigned* const colx = (unsigned*)(wsb + OFF_COLX);
  float* const pb = (float*)(wsb + OFF_PB);

  // ---- one-time LDS init from packed ws ----
  {
    const unsigned* s0 = (const unsigned*)(wsb + OFF_W0H) + cw * 4736;
    unsigned* d0 = (unsigned*)W0H_;
    for (int i = tid; i < 4736; i += TPB) d0[i] = s0[i];
    const unsigned* s1 = (const unsigned*)(wsb + OFF_W1AH) + cw * 4096;
    const unsigned* s2 = (const unsigned*)(wsb + OFF_W1AL) + cw * 4096;
    const unsigned* s3 = (const unsigned*)(wsb + OFF_W1BH) + cw * 4096;
    const unsigned* s4 = (const unsigned*)(wsb + OFF_W1BL) + cw * 4096;
    unsigned* d1 = (unsigned*)W1AH_; unsigned* d2 = (unsigned*)W1AL_;
    unsigned* d3 = (unsigned*)W1BH_; unsigned* d4 = (unsigned*)W1BL_;
    for (int i = tid; i < 4096; i += TPB) {
      const int c = i >> 7, d = i & 127;  // restride 128 -> 132 dwords
      d1[c * 132 + d] = s1[i];
      d2[c * 132 + d] = s2[i];
      d3[c * 132 + d] = s3[i];
      d4[c * 132 + d] = s4[i];
    }
    for (int i = tid; i < 2048; i += TPB)
      WLIN_[(i >> 8) * 260 + (i & 255)] = Wlin[i];
    if (tid < 32) {
      const int J = (tid >> 3) * 256 + cw * 8 + (tid & 7);
      B0_[tid] = bih0[J] + bhh0[J];
      B1_[tid] = bih1[J] + bhh1[J];
    }
    if (tid < 8) BLIN_[tid] = blin[tid];
    {  // permanent zero pad k=16..31 of AB
      const int r = tid >> 3, q = tid & 7;
      ((unsigned*)ABH_)[r * 148 + 8 + q] = 0u;
      ((unsigned*)ABL_)[r * 148 + 8 + q] = 0u;
    }
  }
  // grid barrier 1: everyone done READING overlay weight regions
  __syncthreads();
  if (tid == 0) {
    __hip_atomic_fetch_add(&ctrl[IB1_U], 1u, __ATOMIC_RELAXED,
                           __HIP_MEMORY_SCOPE_AGENT);
    while (rload(&ctrl[IB1_U]) < NWG) __builtin_amdgcn_s_sleep(1);
  }
  __syncthreads();
  // zero OWN (sl,cw) exchange ranges (both parities)
  {
    const int b = sl * 8192 + cw * 256 + tid;
    mall_store_u32(h0x + b, 0u);
    mall_store_u32(h0x + 65536 + b, 0u);
    mall_store_u32(h1x + b, 0u);
    mall_store_u32(h1x + 65536 + b, 0u);
    vmdrain();
  }
  // grid barrier 2: zeroing visible before any exchange
  __syncthreads();
  if (tid == 0) {
    __hip_atomic_fetch_add(&ctrl[IB2_U], 1u, __ATOMIC_RELAXED,
                           __HIP_MEMORY_SCOPE_AGENT);
    while (rload(&ctrl[IB2_U]) < NWG) __builtin_amdgcn_s_sleep(1);
  }
  __syncthreads();

  // per-thread constants
  const int l = tid & 63, wv = tid >> 6;
  const int frow = ((wv >> 1) << 4) + (l & 15);
  const int fcol = ((wv & 1) << 4) + (l & 15);
  const int kg = (l >> 4) << 3;
  const int gr = ((wv >> 1) << 4) + ((l >> 4) << 2);
  const int rA = tid >> 3, uA = tid & 7;
  const int pr = tid >> 3, pc32 = (tid & 7) << 5;   // gather pattern

  float c0s = 0.f, c1s = 0.f;

  for (int g = 0; g < 127; ++g) {
    const int s = (g - sl) & 7;
    const int t = g - s;
    if (t < 0 || t > 119) continue;
    const bool fresh = (s == 0);
    const int gb = g & 1;                                   // buffer parity
    const unsigned tagv = 1u | (((unsigned)(g >> 1) & 1u) << 1);
    const int gbp = (g - 1) & 1;                            // prev parity
    const unsigned tagp = 1u | (((unsigned)((g - 1) >> 1) & 1u) << 1);

    // ---- P: prefetch h1X(g-1) -- fire-and-forget; data ~7us old ----
    f32x4 p0, p1, p2, p3, p4, p5, p6, p7;
    const unsigned* h1src = h1x + gbp * 65536 + sl * 8192 + pr * 256 + pc32;
    if (!fresh) {
      mall_issue8x4(h1src, p0, p1, p2, p3, p4, p5, p6, p7);
    }

    // ---- A: L0 h0-part (16 MFMA; pre-colX compute) ----
    f32x4 acc0;
    { const float b = B0_[fcol]; acc0 = (f32x4){b, b, b, b}; }
    if (!fresh) {
      for (int ks = 0; ks < 8; ++ks) {
        const f16x8 ah = *(const f16x8*)(ABH_ + frow * 296 + 32 + ks * 32 + kg);
        const f16x8 al = *(const f16x8*)(ABL_ + frow * 296 + 32 + ks * 32 + kg);
        const f16x8 wh = *(const f16x8*)(W0H_ + fcol * 296 + 32 + ks * 32 + kg);
        acc0 = mfma16(ah, wh, acc0);
        acc0 = mfma16(al, wh, acc0);
      }
    }

    // ---- D: stage x -> AB[0..15] (colX MALL poll for feedback dims) ----
    {
      const int r = tid >> 3, dp = (tid & 7) << 1;
      unsigned hw, lw;
      if (t <= 7 && s < 8 - t) {
        const float* tp = traj + r * 2048 + (t + s) * 16 + dp;
        splitpack(tp[0], tp[1], hw, lw);
      } else if (dp < 8) {
        const int ti = (t <= 7) ? (2 * t + s - 1) : (t + s);
        const float* tp = traj + r * 2048 + ti * 16 + dp;
        splitpack(tp[0], tp[1], hw, lw);
      } else {
        const unsigned* cp = colx + (g - 8) * 256 + r * 8 + (dp - 8);
        unsigned w0, w1;
        int fails = 0;
        while (true) {
          mall_load2(cp, w0, w1);
          if ((w0 & 0x10000u) && (w1 & 0x10000u)) break;
          if (++fails > 4) __builtin_amdgcn_s_sleep(1);
        }
        hw = (w0 & 0xffffu) | ((w1 & 0xffffu) << 16);
        lw = (w0 >> 16) | (w1 & 0xffff0000u);
        if (s == 7) {  // cache finisher base out[:,t-1]
          BASE_[r * 8 + dp - 8] = uf16(w0 & 0xffffu) + uf16(w0 >> 16);
          BASE_[r * 8 + dp - 7] = uf16(w1 & 0xffffu) + uf16(w1 >> 16);
        }
      }
      ((unsigned*)ABH_)[r * 148 + (dp >> 1)] = hw;
      ((unsigned*)ABL_)[r * 148 + (dp >> 1)] = lw;
    }
    __syncthreads();

    // ---- E: L0 x k-step, gates out ----
    {
      const f16x8 ah = *(const f16x8*)(ABH_ + frow * 296 + kg);
      const f16x8 al = *(const f16x8*)(ABL_ + frow * 296 + kg);
      const f16x8 wh = *(const f16x8*)(W0H_ + fcol * 296 + kg);
      acc0 = mfma16(ah, wh, acc0);
      acc0 = mfma16(al, wh, acc0);
#pragma unroll
      for (int q = 0; q < 4; ++q) GATES_[(gr + q) * 33 + fcol] = acc0[q];
    }
    __syncthreads();

    // ---- Fblk: land prefetched h1 -> H1H_ (memory-quiet), L0 act + h0X ----
    if (!fresh) {
      vmdrain();                              // prefetch long done (~free)
      __builtin_amdgcn_sched_barrier(0);      // no reads hoisted above wait
      const unsigned ok = TG4(p0,tagp) & TG4(p1,tagp) & TG4(p2,tagp) &
                          TG4(p3,tagp) & TG4(p4,tagp) & TG4(p5,tagp) &
                          TG4(p6,tagp) & TG4(p7,tagp);
      if (!ok) {  // straggler (rare): spin-fix
        f32x4 v0, v1, v2, v3, v4, v5, v6, v7;
        POLL8(h1src, tagp)
        p0 = v0; p1 = v1; p2 = v2; p3 = v3;
        p4 = v4; p5 = v5; p6 = v6; p7 = v7;
      }
      unsigned* dst = (unsigned*)H1H_ + pr * 132 + (pc32 >> 1);
      PKH(p0, 0)  PKH(p1, 2)  PKH(p2, 4)  PKH(p3, 6)
      PKH(p4, 8)  PKH(p5, 10) PKH(p6, 12) PKH(p7, 14)
    }
    {
      const float iv = GATES_[rA * 33 + uA];
      const float fv = GATES_[rA * 33 + 8 + uA];
      const float gv = GATES_[rA * 33 + 16 + uA];
      const float ov = GATES_[rA * 33 + 24 + uA];
      const float cold = fresh ? 0.f : c0s;
      const float cn = sigf(fv) * cold + sigf(iv) * tanhfast(gv);
      c0s = cn;
      const float hv = sigf(ov) * tanhfast(cn);
      const _Float16 hh = (_Float16)hv;
      unsigned lo = f16u((_Float16)(hv - (float)hh));
      lo = (lo & 0xFFFCu) | tagv;
      mall_store_u32(h0x + gb * 65536 + sl * 8192 + rA * 256 + cw * 8 + uA,
                     f16u(hh) | (lo << 16));
      if (g == 126) {
        out[30720 + rA * 256 + cw * 8 + uA] = hv;   // h_n L0
        out[47104 + rA * 256 + cw * 8 + uA] = cn;   // c_n L0
      }
    }
    __syncthreads();   // H1H_ writes visible for B'

    // ---- B': W1B*h1 (16 MFMA, memory-quiet; fills h0X window) ----
    f32x4 acc1;
    { const float b = B1_[fcol]; acc1 = (f32x4){b, b, b, b}; }
    if (!fresh) {
      for (int ks = 0; ks < 8; ++ks) {
        const f16x8 hh = *(const f16x8*)(H1H_ + frow * 264 + ks * 32 + kg);
        const f16x8 wh = *(const f16x8*)(W1BH_ + fcol * 264 + ks * 32 + kg);
        const f16x8 wl = *(const f16x8*)(W1BL_ + fcol * 264 + ks * 32 + kg);
        acc1 = mfma16(hh, wh, acc1);
        acc1 = mfma16(hh, wl, acc1);
      }
    }

    // ---- H: poll-gather h0X (tag g) -> unpack into AB[32..287] ----
    {
      const unsigned* src = h0x + gb * 65536 + sl * 8192 + pr * 256 + pc32;
      f32x4 v0, v1, v2, v3, v4, v5, v6, v7;
      POLL8(src, tagv)
      unsigned* ah32 = (unsigned*)ABH_ + pr * 148 + 16 + (pc32 >> 1);
      unsigned* al32 = (unsigned*)ABL_ + pr * 148 + 16 + (pc32 >> 1);
      UNPK(v0, 0)  UNPK(v1, 2)  UNPK(v2, 4)  UNPK(v3, 6)
      UNPK(v4, 8)  UNPK(v5, 10) UNPK(v6, 12) UNPK(v7, 14)
    }
    __syncthreads();

    // ---- I: L1 W1A part (24 MFMA), gates out ----
    {
      for (int ks = 0; ks < 8; ++ks) {
        const f16x8 ah = *(const f16x8*)(ABH_ + frow * 296 + 32 + ks * 32 + kg);
        const f16x8 al = *(const f16x8*)(ABL_ + frow * 296 + 32 + ks * 32 + kg);
        const f16x8 wh = *(const f16x8*)(W1AH_ + fcol * 264 + ks * 32 + kg);
        const f16x8 wl = *(const f16x8*)(W1AL_ + fcol * 264 + ks * 32 + kg);
        acc1 = mfma16(ah, wh, acc1);
        acc1 = mfma16(al, wh, acc1);
        acc1 = mfma16(ah, wl, acc1);
      }
#pragma unroll
      for (int q = 0; q < 4; ++q) GATES_[(gr + q) * 33 + fcol] = acc1[q];
    }
    __syncthreads();

    // ---- J: L1 act; HOWN; h1X store (s<7 only; consumed via prefetch) ----
    {
      const float iv = GATES_[rA * 33 + uA];
      const float fv = GATES_[rA * 33 + 8 + uA];
      const float gv = GATES_[rA * 33 + 16 + uA];
      const float ov = GATES_[rA * 33 + 24 + uA];
      const float cold = fresh ? 0.f : c1s;
      const float cn = sigf(fv) * cold + sigf(iv) * tanhfast(gv);
      c1s = cn;
      const float hv = sigf(ov) * tanhfast(cn);
      HOWN_[rA * 9 + uA] = hv;
      if (s < 7) {
        const _Float16 hh = (_Float16)hv;
        unsigned lo = f16u((_Float16)(hv - (float)hh));
        lo = (lo & 0xFFFCu) | tagv;
        mall_store_u32(h1x + gb * 65536 + sl * 8192 + rA * 256 + cw * 8 + uA,
                       f16u(hh) | (lo << 16));
      }
      if (g == 126) {
        out[38912 + rA * 256 + cw * 8 + uA] = hv;   // h_n L1
        out[55296 + rA * 256 + cw * 8 + uA] = cn;   // c_n L1
      }
    }

    // ---- finishing slot only: PB partials + funnel (wg-uniform branch) ----
    if (s == 7) {
      __syncthreads();   // HOWN_ complete
      {
        const float* wl = WLIN_ + uA * 260 + cw * 8;
        const float* hb = HOWN_ + (tid >> 3) * 9;
        float p = 0.f;
#pragma unroll
        for (int u = 0; u < 8; ++u) p = fmaf(hb[u], wl[u], p);
        unsigned pu = (fbits(p) & ~3u) | tagv;
        mall_store_u32((unsigned*)pb + gb * 8192 + tid * 32 + cw, pu);
      }
      if (cw == 0) {
        const float* src = pb + gb * 8192 + tid * 32;
        f32x4 v0, v1, v2, v3, v4, v5, v6, v7;
        POLLPB(src, tagv)
        float pred = BLIN_[uA]
            + v0.x + v0.y + v0.z + v0.w + v1.x + v1.y + v1.z + v1.w
            + v2.x + v2.y + v2.z + v2.w + v3.x + v3.y + v3.z + v3.w
            + v4.x + v4.y + v4.z + v4.w + v5.x + v5.y + v5.z + v5.w
            + v6.x + v6.y + v6.z + v6.w + v7.x + v7.y + v7.z + v7.w;
        const float base = (t == 0) ? traj[rA * 2048 + 7 * 16 + 8 + uA]
                                    : BASE_[tid];
        const float v = base + pred;
        out[rA * 960 + t * 8 + uA] = v;             // exact f32 result
        const _Float16 hh = (_Float16)v;            // tagged mirror for feedback
        unsigned lo = f16u((_Float16)(v - (float)hh));
        lo = (lo & 0xFFFEu) | 1u;
        mall_store_u32(colx + t * 256 + tid, f16u(hh) | (lo << 16));
        vmdrain();
      }
    }
  }
}

extern "C" void kernel_launch(void* const* d_in, const int* in_sizes, int n_in,
                              void* d_out, int out_size, void* d_ws, size_t ws_size,
                              hipStream_t stream) {
  (void)in_sizes; (void)n_in; (void)out_size; (void)ws_size;
  const float* traj = (const float*)d_in[0];
  const float* Wih0 = (const float*)d_in[1];
  const float* Whh0 = (const float*)d_in[2];
  const float* bih0 = (const float*)d_in[3];
  const float* bhh0 = (const float*)d_in[4];
  const float* Wih1 = (const float*)d_in[5];
  const float* Whh1 = (const float*)d_in[6];
  const float* bih1 = (const float*)d_in[7];
  const float* bhh1 = (const float*)d_in[8];
  const float* Wlin = (const float*)d_in[9];
  const float* blin = (const float*)d_in[10];
  float* out = (float*)d_out;
  char* wsb = (char*)d_ws;

  static bool attr_done = false;
  if (!attr_done) {
    (void)hipFuncSetAttribute((const void*)lstm_main,
                              hipFuncAttributeMaxDynamicSharedMemorySize,
                              SMEM_BYTES);
    attr_done = true;
  }

  hipMemsetAsync(d_ws, 0, CTRL_BYTES, stream);
  hipMemsetAsync(wsb + OFF_COLX, 0, PBCOLX_BYTES, stream);
  lstm_prep<<<1184, 256, 0, stream>>>(Wih0, Whh0, Wih1, Whh1, wsb);

  void* args[] = {(void*)&traj, (void*)&bih0, (void*)&bhh0, (void*)&bih1,
                  (void*)&bhh1, (void*)&Wlin, (void*)&blin, (void*)&out,
                  (void*)&wsb};
  hipLaunchCooperativeKernel((void*)lstm_main, dim3(NWG), dim3(TPB), args,
                             SMEM_BYTES, stream);
}